// Round 4
// baseline (261.442 us; speedup 1.0000x reference)
//
#include <hip/hip_runtime.h>
#include <math.h>

// Retention (B=4, S=4096, D=256): chunkwise, split-bf16 MFMA, packed k8-slab
// operands, async global->LDS staging, bank-conflict-free padded LDS.
#define BB 4
#define SS 4096
#define DD 256
#define LL 256
#define NCH 16
#define GAMMA 0.9865f
#define LOG2G (-0.019609034f)   // log2(0.9865)
#define INV1MG 74.07407407f     // 1/(1-gamma)
#define SLAB 1040               // padded LDS slab stride in u16 (2080 B: +8 banks/quad)

typedef __attribute__((ext_vector_type(8))) short short8;
typedef __attribute__((ext_vector_type(4))) float f32x4;
typedef unsigned short u16;
typedef unsigned int u32;

__device__ __forceinline__ u16 f2bf(float f) {
  union { float f; unsigned u; } v; v.f = f;
  unsigned r = v.u + 0x7FFFu + ((v.u >> 16) & 1u);
  return (u16)(r >> 16);
}
__device__ __forceinline__ float bf2f(u16 h) {
  union { unsigned u; float f; } v; v.u = ((unsigned)h) << 16; return v.f;
}

// async global->LDS, 16B/lane; LDS dest = wave-uniform base + lane*16
__device__ __forceinline__ void gll16(const u16* g, u16* l) {
  __builtin_amdgcn_global_load_lds(
      (const __attribute__((address_space(1))) u32*)g,
      (__attribute__((address_space(3))) u32*)l, 16, 0, 0);
}
// stage one BK=32 k-step (4 dense global slabs of 1024 u16) into padded LDS
__device__ __forceinline__ void stage8kp(const u16* g, u16* l, int lane) {
#pragma unroll
  for (int i = 0; i < 8; ++i)
    gll16(g + i * 512 + lane * 8, l + (i >> 1) * SLAB + (i & 1) * 512);
}

// MFMA: 128x128 tile, BK=32, 4 waves (64x64), split-bf16 3-product.
__device__ __forceinline__ void mfma_step_slab(
    const u16* Ah, const u16* Al, const u16* Bh, const u16* Bl,
    int wm0, int wn0, int fm, int fq, f32x4 acc[4][4])
{
  const int ka = fq * SLAB;
  short8 ah[4], al[4];
#pragma unroll
  for (int i = 0; i < 4; ++i) {
    ah[i] = *(const short8*)&Ah[ka + (wm0 + i * 16 + fm) * 8];
    al[i] = *(const short8*)&Al[ka + (wm0 + i * 16 + fm) * 8];
  }
#pragma unroll
  for (int j = 0; j < 4; ++j) {
    short8 bh = *(const short8*)&Bh[ka + (wn0 + j * 16 + fm) * 8];
    short8 bl = *(const short8*)&Bl[ka + (wn0 + j * 16 + fm) * 8];
#pragma unroll
    for (int i = 0; i < 4; ++i) {
      acc[i][j] = __builtin_amdgcn_mfma_f32_16x16x32_bf16(al[i], bh, acc[i][j], 0, 0, 0);
      acc[i][j] = __builtin_amdgcn_mfma_f32_16x16x32_bf16(ah[i], bl, acc[i][j], 0, 0, 0);
      acc[i][j] = __builtin_amdgcn_mfma_f32_16x16x32_bf16(ah[i], bh, acc[i][j], 0, 0, 0);
    }
  }
}

// ---------------------------------------------------------------------------
// 0a) pack W^T into dense slab layout, split hi/lo
__global__ __launch_bounds__(256) void packW_kernel(
    const float* __restrict__ Wq, const float* __restrict__ Wk, const float* __restrict__ Wv,
    u16* __restrict__ Wth, u16* __restrict__ Wtl)
{
  const int which = blockIdx.x, pn = blockIdx.y;
  const float* W = which == 0 ? Wq : (which == 1 ? Wk : Wv);
  const int t = threadIdx.x;
  for (int it = 0; it < 16; ++it) {
    int pos = it * 256 + t;
    int k8 = pos >> 7, r = pos & 127;
    u16 hs[8], ls[8];
#pragma unroll
    for (int u = 0; u < 8; ++u) {
      float x = W[(size_t)(k8 * 8 + u) * DD + pn * 128 + r];
      u16 h = f2bf(x); hs[u] = h; ls[u] = f2bf(x - bf2f(h));
    }
    size_t o = ((size_t)((which * 2 + pn) * 32 + k8)) * 1024 + (size_t)r * 8;
    *(short8*)&Wth[o] = *(short8*)hs;
    *(short8*)&Wtl[o] = *(short8*)ls;
  }
}

// 0b) split X (xq|xk|xv) into packed slab hi/lo; coalesced via LDS bounce
__global__ __launch_bounds__(256) void splitX_kernel(
    const float* __restrict__ xq, const float* __restrict__ xk, const float* __restrict__ xv,
    u16* __restrict__ Xh, u16* __restrict__ Xl)
{
  const int panel = blockIdx.x, which = blockIdx.y;
  const float* X = which == 0 ? xq : (which == 1 ? xk : xv);
  __shared__ float tile[64][132];
  const int t = threadIdx.x;
  const size_t rbase = (size_t)panel * 128 * DD;
  const size_t obase = (size_t)(which * 128 + panel) * 32768;
  for (int q = 0; q < 4; ++q) {          // 64-row halves x 2 passes? q: row-half(2) x k-half(2)
    int rh = q >> 1, kh = q & 1;         // rows rh*64..+64, k kh*128..+128
    __syncthreads();
#pragma unroll
    for (int v = 0; v < 8; ++v) {
      int lin = v * 256 + t;
      int col4 = lin & 31, row = lin >> 5;
      float4 x = *(const float4*)&X[rbase + (size_t)(rh * 64 + row) * DD + kh * 128 + col4 * 4];
      *(float4*)&tile[row][col4 * 4] = x;
    }
    __syncthreads();
#pragma unroll
    for (int it = 0; it < 4; ++it) {
      int unit = it * 256 + t;           // 16 slabs-halves x 64 rows
      int sl = unit >> 6, row = unit & 63;
      u16 hs[8], ls[8];
#pragma unroll
      for (int u = 0; u < 8; ++u) {
        float x = tile[row][sl * 8 + u];
        u16 h = f2bf(x); hs[u] = h; ls[u] = f2bf(x - bf2f(h));
      }
      size_t o = obase + (size_t)(kh * 16 + sl) * 1024 + (size_t)(rh * 64 + row) * 8;
      *(short8*)&Xh[o] = *(short8*)hs;
      *(short8*)&Xl[o] = *(short8*)ls;
    }
  }
}

// ---------------------------------------------------------------------------
// 1) projections (all-async staging): Q~=(xWq+b)/16, K~=(xWk+b)/sqrt(c), V.
__global__ __launch_bounds__(256, 3) void proj_kernel(
    const u16* __restrict__ Xh, const u16* __restrict__ Xl,
    const u16* __restrict__ Wth, const u16* __restrict__ Wtl,
    const float* __restrict__ bq, const float* __restrict__ bk_, const float* __restrict__ bv,
    u16* __restrict__ Qh, u16* __restrict__ Ql,
    u16* __restrict__ Kh, u16* __restrict__ Kl,
    u16* __restrict__ KTh, u16* __restrict__ KTl, float* __restrict__ VT32)
{
  const int which = blockIdx.z;
  const float* bias = which == 0 ? bq : (which == 1 ? bk_ : bv);
  const int m0 = blockIdx.x * 128;  // global row over B*S
  const int pn = blockIdx.y;        // output n-panel
  __shared__ u16 Ah[4 * SLAB], Al[4 * SLAB], Bh[4 * SLAB], Bl[4 * SLAB];
  const int tid = threadIdx.x, lane = tid & 63, wave = tid >> 6;
  const int wm0 = (wave >> 1) * 64, wn0 = (wave & 1) * 64;
  const int fm = lane & 15, fq = lane >> 4;
  const u16* XhP = Xh + (size_t)(which * 128 + (m0 >> 7)) * 32768;
  const u16* XlP = Xl + (size_t)(which * 128 + (m0 >> 7)) * 32768;
  const u16* WhP = Wth + (size_t)((which * 2 + pn) * 32) * 1024;
  const u16* WlP = Wtl + (size_t)((which * 2 + pn) * 32) * 1024;
  f32x4 acc[4][4];
#pragma unroll
  for (int i = 0; i < 4; ++i)
#pragma unroll
    for (int j = 0; j < 4; ++j) acc[i][j] = (f32x4){0.f, 0.f, 0.f, 0.f};
  for (int ks = 0; ks < 8; ++ks) {
    __syncthreads();
    if (wave == 0) stage8kp(XhP + ks * 4096, Ah, lane);
    if (wave == 1) stage8kp(XlP + ks * 4096, Al, lane);
    if (wave == 2) stage8kp(WhP + ks * 4096, Bh, lane);
    if (wave == 3) stage8kp(WlP + ks * 4096, Bl, lane);
    __syncthreads();
    mfma_step_slab(Ah, Al, Bh, Bl, wm0, wn0, fm, fq, acc);
  }
#pragma unroll
  for (int i = 0; i < 4; ++i)
#pragma unroll
    for (int j = 0; j < 4; ++j) {
      const int grow0 = m0 + wm0 + i * 16 + fq * 4;
      const int gcol = pn * 128 + wn0 + j * 16 + fm;
      const float bs = bias[gcol];
      if (which == 0) {
#pragma unroll
        for (int r = 0; r < 4; ++r) {
          int grow = grow0 + r;
          float q = (acc[i][j][r] + bs) * (1.f / 16.f);
          size_t o = ((size_t)((grow >> 7) * 32 + (gcol >> 3))) * 1024 + (grow & 127) * 8 + (gcol & 7);
          u16 h = f2bf(q); Qh[o] = h; Ql[o] = f2bf(q - bf2f(h));
        }
      } else if (which == 1) {
        u16 th[4], tl[4];
#pragma unroll
        for (int r = 0; r < 4; ++r) {
          int grow = grow0 + r, sb = grow & (SS - 1);
          float cj = (1.0f - exp2f((float)(sb + 1) * LOG2G)) * INV1MG;
          float kq = (acc[i][j][r] + bs) * rsqrtf(cj);
          size_t o = ((size_t)((grow >> 7) * 32 + (gcol >> 3))) * 1024 + (grow & 127) * 8 + (gcol & 7);
          u16 h = f2bf(kq), l = f2bf(kq - bf2f(h));
          Kh[o] = h; Kl[o] = l; th[r] = h; tl[r] = l;
        }
        int b = grow0 >> 12, sb0 = grow0 & (SS - 1);
        size_t o = ((size_t)((b * 2 + (gcol >> 7)) * 512 + (sb0 >> 3))) * 1024 + (gcol & 127) * 8 + (sb0 & 7);
        uint2 ph, pl;
        ph.x = (u32)th[0] | ((u32)th[1] << 16); ph.y = (u32)th[2] | ((u32)th[3] << 16);
        pl.x = (u32)tl[0] | ((u32)tl[1] << 16); pl.y = (u32)tl[2] | ((u32)tl[3] << 16);
        *(uint2*)&KTh[o] = ph; *(uint2*)&KTl[o] = pl;
      } else {
        int b = grow0 >> 12, sb0 = grow0 & (SS - 1);
        float4 w = {acc[i][j][0] + bs, acc[i][j][1] + bs, acc[i][j][2] + bs, acc[i][j][3] + bs};
        *(float4*)&VT32[(size_t)b * DD * SS + (size_t)gcol * SS + sb0] = w;
      }
    }
}

// ---------------------------------------------------------------------------
// 2) per-chunk vector state from KT packed
__global__ __launch_bounds__(256) void local_vec_kernel(
    const u16* __restrict__ KTh, const u16* __restrict__ KTl, float* __restrict__ lVec)
{
  const int chunk = blockIdx.x, b = chunk >> 4, c = chunk & 15;
  const int t = threadIdx.x;
  __shared__ float wt[256];
  wt[t] = exp2f((float)(255 - t) * LOG2G);
  __syncthreads();
  const int pd = t >> 7, dl = t & 127;
  float s = 0.f;
  for (int k8 = 0; k8 < 32; ++k8) {
    size_t o = ((size_t)((b * 2 + pd) * 512 + c * 32 + k8)) * 1024 + dl * 8;
    short8 hv = *(const short8*)&KTh[o];
    short8 lv = *(const short8*)&KTl[o];
#pragma unroll
    for (int u = 0; u < 8; ++u)
      s = fmaf(bf2f((u16)hv[u]) + bf2f((u16)lv[u]), wt[k8 * 8 + u], s);
  }
  lVec[(size_t)chunk * DD + t] = s;
}

__global__ __launch_bounds__(256) void combine_vec_kernel(
    const float* __restrict__ lVec, float* __restrict__ cVec)
{
  const int b = blockIdx.x;
  const int d = threadIdx.x;
  const float gL = powf(GAMMA, (float)LL);
  float s = 0.f;
  for (int c = 0; c < NCH; ++c) {
    cVec[(size_t)(b * NCH + c) * DD + d] = s;
    s = gL * s + lVec[(size_t)(b * NCH + c) * DD + d];
  }
}

// ---------------------------------------------------------------------------
// 3) Sg = mask * (Q~.K~) * g^(il-jl), packed split (rows il, k jl)
__global__ __launch_bounds__(256, 3) void scores_kernel(
    const u16* __restrict__ Qh, const u16* __restrict__ Ql,
    const u16* __restrict__ Kh, const u16* __restrict__ Kl,
    u16* __restrict__ Sgh, u16* __restrict__ Sgl)
{
  const int chunk = blockIdx.x, b = chunk >> 4, c = chunk & 15;
  const int ty = blockIdx.y;
  const int m0 = (ty == 0) ? 0 : 128;
  const int n0 = (ty == 2) ? 128 : 0;
  __shared__ u16 Ah[4 * SLAB], Al[4 * SLAB], Bh[4 * SLAB], Bl[4 * SLAB];
  const int tid = threadIdx.x, lane = tid & 63, wave = tid >> 6;
  const int wm0 = (wave >> 1) * 64, wn0 = (wave & 1) * 64;
  const int fm = lane & 15, fq = lane >> 4;
  const u16* QhP = Qh + (size_t)((b * SS + c * LL + m0) >> 7) * 32768;
  const u16* QlP = Ql + (size_t)((b * SS + c * LL + m0) >> 7) * 32768;
  const u16* KhP = Kh + (size_t)((b * SS + c * LL + n0) >> 7) * 32768;
  const u16* KlP = Kl + (size_t)((b * SS + c * LL + n0) >> 7) * 32768;
  f32x4 acc[4][4];
#pragma unroll
  for (int i = 0; i < 4; ++i)
#pragma unroll
    for (int j = 0; j < 4; ++j) acc[i][j] = (f32x4){0.f, 0.f, 0.f, 0.f};
  for (int ks = 0; ks < 8; ++ks) {
    __syncthreads();
    if (wave == 0) stage8kp(QhP + ks * 4096, Ah, lane);
    if (wave == 1) stage8kp(QlP + ks * 4096, Al, lane);
    if (wave == 2) stage8kp(KhP + ks * 4096, Bh, lane);
    if (wave == 3) stage8kp(KlP + ks * 4096, Bl, lane);
    __syncthreads();
    mfma_step_slab(Ah, Al, Bh, Bl, wm0, wn0, fm, fq, acc);
  }
  const int ps = chunk * 2 + (m0 >> 7);
#pragma unroll
  for (int i = 0; i < 4; ++i)
#pragma unroll
    for (int j = 0; j < 4; ++j) {
      const int il0 = m0 + wm0 + i * 16 + fq * 4;
      const int jl = n0 + wn0 + j * 16 + fm;
#pragma unroll
      for (int r = 0; r < 4; ++r) {
        int il = il0 + r;
        float v = (jl <= il) ? acc[i][j][r] * exp2f((float)(il - jl) * LOG2G) : 0.f;
        size_t o = ((size_t)(ps * 32 + (jl >> 3))) * 1024 + (il & 127) * 8 + (jl & 7);
        u16 h = f2bf(v); Sgh[o] = h; Sgl[o] = f2bf(v - bf2f(h));
      }
    }
}

// ---------------------------------------------------------------------------
// 4) fused: denom (per half-chunk panel) + V scaling -> VdT, VwT splits
__global__ __launch_bounds__(256) void denom_vscale_kernel(
    const u16* __restrict__ Sgh, const u16* __restrict__ Sgl,
    const u16* __restrict__ Qh, const u16* __restrict__ Ql,
    const float* __restrict__ cVec, const float* __restrict__ VT32,
    u16* __restrict__ VdTh, u16* __restrict__ VdTl,
    u16* __restrict__ VwTh, u16* __restrict__ VwTl)
{
  const int p = blockIdx.x;  // 128 panels: b(2) x c(16) x half(2)
  const int half = p & 1, c = (p >> 1) & 15, b = p >> 5;
  const int tid = threadIdx.x, lane = tid & 63, wave = tid >> 6;
  __shared__ float cv[256];
  __shared__ float sdn[128];
  __shared__ float tile[64][132];
  cv[tid] = cVec[(size_t)(b * NCH + c) * DD + tid];
  __syncthreads();
  // --- phase 1: denom for the 128 rows of this panel ---
  const int k8 = lane & 31, sub = lane >> 5;
  const int nslab = half ? 32 : 16;
  const size_t sgbase = (size_t)p * 32768;
  const size_t qbase = (size_t)(b * 32 + c * 2 + half) * 32768;
  for (int rp = 0; rp < 16; ++rp) {
    int r = wave * 32 + rp * 2 + sub;
    float rsum = 0.f, dt = 0.f;
    {
      size_t oq = qbase + (size_t)k8 * 1024 + r * 8;
      short8 qh = *(const short8*)&Qh[oq];
      short8 ql = *(const short8*)&Ql[oq];
#pragma unroll
      for (int u = 0; u < 8; ++u)
        dt = fmaf(bf2f((u16)qh[u]) + bf2f((u16)ql[u]), cv[k8 * 8 + u], dt);
    }
    if (k8 < nslab) {
      size_t os = sgbase + (size_t)k8 * 1024 + r * 8;
      short8 sh = *(const short8*)&Sgh[os];
      short8 sl = *(const short8*)&Sgl[os];
#pragma unroll
      for (int u = 0; u < 8; ++u)
        rsum += bf2f((u16)sh[u]) + bf2f((u16)sl[u]);
    }
#pragma unroll
    for (int off = 16; off >= 1; off >>= 1) {
      rsum += __shfl_down(rsum, off, 32);
      dt += __shfl_down(dt, off, 32);
    }
    if ((lane & 31) == 0) {
      int il = half * 128 + r;
      float rs = exp2f((float)(il + 1) * LOG2G) * dt + rsum;
      sdn[r] = fmaxf(fabsf(rs), 1.0f);
    }
  }
  // --- phase 2: scale V columns s in this panel's range, write packed ---
  const int sbase = c * LL + half * 128;  // within batch
  for (int itE = 0; itE < 4; ++itE) {
    int e0 = itE * 64;
    __syncthreads();
#pragma unroll
    for (int v = 0; v < 8; ++v) {
      int lin = v * 256 + tid;
      int col4 = lin & 31, row = lin >> 5;
      float4 x = *(const float4*)&VT32[(size_t)b * DD * SS + (size_t)(e0 + row) * SS + sbase + col4 * 4];
      *(float4*)&tile[row][col4 * 4] = x;
    }
    __syncthreads();
#pragma unroll
    for (int it = 0; it < 4; ++it) {
      int unit = it * 256 + tid;          // 16 s8-chunks x 64 e-rows
      int s8l = unit >> 6, el = unit & 63;
      int e = e0 + el;
      u16 dh[8], dl_[8], wh[8], wl[8];
#pragma unroll
      for (int u = 0; u < 8; ++u) {
        int rloc = s8l * 8 + u;
        float vd = tile[el][rloc] / sdn[rloc];
        float w = exp2f((float)(255 - (half * 128 + rloc)) * LOG2G);
        float vw = vd * w;
        u16 h = f2bf(vd); dh[u] = h; dl_[u] = f2bf(vd - bf2f(h));
        u16 h2 = f2bf(vw); wh[u] = h2; wl[u] = f2bf(vw - bf2f(h2));
      }
      int s8g = c * 32 + half * 16 + s8l;
      size_t o = ((size_t)((b * 2 + (e >> 7)) * 512 + s8g)) * 1024 + (e & 127) * 8;
      *(short8*)&VdTh[o] = *(short8*)dh; *(short8*)&VdTl[o] = *(short8*)dl_;
      *(short8*)&VwTh[o] = *(short8*)wh; *(short8*)&VwTl[o] = *(short8*)wl;
    }
  }
}

// ---------------------------------------------------------------------------
// 5) lMatT[e][d] = sum_jl Vw[jl,e] K~[jl,d]
__global__ __launch_bounds__(256, 3) void lmat_kernel(
    const u16* __restrict__ VwTh, const u16* __restrict__ VwTl,
    const u16* __restrict__ KTh, const u16* __restrict__ KTl,
    float* __restrict__ lMatT)
{
  const int chunk = blockIdx.x, b = chunk >> 4, c = chunk & 15;
  const int ty = blockIdx.y;
  const int m0 = (ty >> 1) * 128, n0 = (ty & 1) * 128;
  __shared__ u16 Ah[4 * SLAB], Al[4 * SLAB], Bh[4 * SLAB], Bl[4 * SLAB];
  const int tid = threadIdx.x, lane = tid & 63, wave = tid >> 6;
  const int wm0 = (wave >> 1) * 64, wn0 = (wave & 1) * 64;
  const int fm = lane & 15, fq = lane >> 4;
  const u16* AhP = VwTh + ((size_t)(b * 2 + (m0 >> 7)) * 512 + c * 32) * 1024;
  const u16* AlP = VwTl + ((size_t)(b * 2 + (m0 >> 7)) * 512 + c * 32) * 1024;
  const u16* BhP = KTh + ((size_t)(b * 2 + (n0 >> 7)) * 512 + c * 32) * 1024;
  const u16* BlP = KTl + ((size_t)(b * 2 + (n0 >> 7)) * 512 + c * 32) * 1024;
  f32x4 acc[4][4];
#pragma unroll
  for (int i = 0; i < 4; ++i)
#pragma unroll
    for (int j = 0; j < 4; ++j) acc[i][j] = (f32x4){0.f, 0.f, 0.f, 0.f};
  for (int ks = 0; ks < 8; ++ks) {
    __syncthreads();
    if (wave == 0) stage8kp(AhP + ks * 4096, Ah, lane);
    if (wave == 1) stage8kp(AlP + ks * 4096, Al, lane);
    if (wave == 2) stage8kp(BhP + ks * 4096, Bh, lane);
    if (wave == 3) stage8kp(BlP + ks * 4096, Bl, lane);
    __syncthreads();
    mfma_step_slab(Ah, Al, Bh, Bl, wm0, wn0, fm, fq, acc);
  }
#pragma unroll
  for (int i = 0; i < 4; ++i)
#pragma unroll
    for (int j = 0; j < 4; ++j)
#pragma unroll
      for (int r = 0; r < 4; ++r) {
        int e = m0 + wm0 + i * 16 + fq * 4 + r;
        int d = n0 + wn0 + j * 16 + fm;
        lMatT[(size_t)chunk * 65536 + (size_t)e * 256 + d] = acc[i][j][r];
      }
}

// 6) carry scan -> cM packed split (rows e, k d)
__global__ __launch_bounds__(256) void combine_mat_kernel(
    const float* __restrict__ lMatT, u16* __restrict__ cMh, u16* __restrict__ cMl)
{
  const int t = blockIdx.x * 256 + threadIdx.x;  // 32768: b x k8 x e
  const int b = t >> 13, rem = t & 8191;
  const int k8 = rem >> 8, e = rem & 255;
  const float gL = powf(GAMMA, (float)LL);
  float s[8] = {0.f, 0.f, 0.f, 0.f, 0.f, 0.f, 0.f, 0.f};
  for (int ch = 0; ch < 16; ++ch) {
    size_t ro = (size_t)(b * 16 + ch) * 65536 + (size_t)e * 256 + k8 * 8;
    float4 a0 = *(const float4*)&lMatT[ro];
    float4 a1 = *(const float4*)&lMatT[ro + 4];
    float vals[8] = {a0.x, a0.y, a0.z, a0.w, a1.x, a1.y, a1.z, a1.w};
    u16 hh[8], ll[8];
#pragma unroll
    for (int u = 0; u < 8; ++u) {
      u16 h = f2bf(s[u]); hh[u] = h; ll[u] = f2bf(s[u] - bf2f(h));
    }
    size_t wo = ((size_t)(((b * 16 + ch) * 2 + (e >> 7)) * 32 + k8)) * 1024 + (e & 127) * 8;
    *(short8*)&cMh[wo] = *(short8*)hh;
    *(short8*)&cMl[wo] = *(short8*)ll;
#pragma unroll
    for (int u = 0; u < 8; ++u) s[u] = gL * s[u] + vals[u];
  }
}

// ---------------------------------------------------------------------------
// 7) out = g^(il+1) * Q~ @ cM^T + Sg @ Vd
__global__ __launch_bounds__(256, 3) void out_kernel(
    const u16* __restrict__ Qh, const u16* __restrict__ Ql,
    const u16* __restrict__ cMh, const u16* __restrict__ cMl,
    const u16* __restrict__ Sgh, const u16* __restrict__ Sgl,
    const u16* __restrict__ VdTh, const u16* __restrict__ VdTl,
    float* __restrict__ out)
{
  const int chunk = blockIdx.x, b = chunk >> 4, c = chunk & 15;
  const int ty = blockIdx.y;
  const int m0 = (ty >> 1) * 128, n0 = (ty & 1) * 128;
  __shared__ u16 Ah[4 * SLAB], Al[4 * SLAB], Bh[4 * SLAB], Bl[4 * SLAB];
  const int tid = threadIdx.x, lane = tid & 63, wave = tid >> 6;
  const int wm0 = (wave >> 1) * 64, wn0 = (wave & 1) * 64;
  const int fm = lane & 15, fq = lane >> 4;
  f32x4 acc[4][4];
#pragma unroll
  for (int i = 0; i < 4; ++i)
#pragma unroll
    for (int j = 0; j < 4; ++j) acc[i][j] = (f32x4){0.f, 0.f, 0.f, 0.f};
  {  // inter: A = Q panel, B = cM panel
    const u16* AhP = Qh + (size_t)(b * 32 + c * 2 + (m0 >> 7)) * 32768;
    const u16* AlP = Ql + (size_t)(b * 32 + c * 2 + (m0 >> 7)) * 32768;
    const u16* BhP = cMh + (size_t)(chunk * 2 + (n0 >> 7)) * 32768;
    const u16* BlP = cMl + (size_t)(chunk * 2 + (n0 >> 7)) * 32768;
    for (int ks = 0; ks < 8; ++ks) {
      __syncthreads();
      if (wave == 0) stage8kp(AhP + ks * 4096, Ah, lane);
      if (wave == 1) stage8kp(AlP + ks * 4096, Al, lane);
      if (wave == 2) stage8kp(BhP + ks * 4096, Bh, lane);
      if (wave == 3) stage8kp(BlP + ks * 4096, Bl, lane);
      __syncthreads();
      mfma_step_slab(Ah, Al, Bh, Bl, wm0, wn0, fm, fq, acc);
    }
  }
#pragma unroll
  for (int i = 0; i < 4; ++i)
#pragma unroll
    for (int r = 0; r < 4; ++r) {
      int il = m0 + wm0 + i * 16 + fq * 4 + r;
      float sc = exp2f((float)(il + 1) * LOG2G);
#pragma unroll
      for (int j = 0; j < 4; ++j) acc[i][j][r] *= sc;
    }
  {  // intra: A = Sg panel, B = VdT panel; k bounded by causality
    const u16* AhP = Sgh + (size_t)(chunk * 2 + (m0 >> 7)) * 32768;
    const u16* AlP = Sgl + (size_t)(chunk * 2 + (m0 >> 7)) * 32768;
    const u16* BhP = VdTh + ((size_t)(b * 2 + (n0 >> 7)) * 512 + c * 32) * 1024;
    const u16* BlP = VdTl + ((size_t)(b * 2 + (n0 >> 7)) * 512 + c * 32) * 1024;
    const int nks = (m0 >> 5) + 4;  // 4 or 8
    for (int ks = 0; ks < nks; ++ks) {
      __syncthreads();
      if (wave == 0) stage8kp(AhP + ks * 4096, Ah, lane);
      if (wave == 1) stage8kp(AlP + ks * 4096, Al, lane);
      if (wave == 2) stage8kp(BhP + ks * 4096, Bh, lane);
      if (wave == 3) stage8kp(BlP + ks * 4096, Bl, lane);
      __syncthreads();
      mfma_step_slab(Ah, Al, Bh, Bl, wm0, wn0, fm, fq, acc);
    }
  }
#pragma unroll
  for (int i = 0; i < 4; ++i)
#pragma unroll
    for (int j = 0; j < 4; ++j)
#pragma unroll
      for (int r = 0; r < 4; ++r) {
        int il = m0 + wm0 + i * 16 + fq * 4 + r;
        int e = n0 + wn0 + j * 16 + fm;
        out[(size_t)(b * SS + c * LL + il) * DD + e] = acc[i][j][r];
      }
}

// ---------------------------------------------------------------------------
extern "C" void kernel_launch(void* const* d_in, const int* in_sizes, int n_in,
                              void* d_out, int out_size, void* d_ws, size_t ws_size,
                              hipStream_t stream) {
  const float* xq = (const float*)d_in[0];
  const float* xk = (const float*)d_in[1];
  const float* xv = (const float*)d_in[2];
  const float* Wq = (const float*)d_in[3];
  const float* bq = (const float*)d_in[4];
  const float* Wk = (const float*)d_in[5];
  const float* bk = (const float*)d_in[6];
  const float* Wv = (const float*)d_in[7];
  const float* bv = (const float*)d_in[8];
  float* out = (float*)d_out;

  char* p = (char*)d_ws;
  const size_t H16 = (size_t)BB * SS * DD * 2;  // 8 MB
  u16* Qh   = (u16*)(p + 0 * H16);  u16* Ql   = (u16*)(p + 1 * H16);
  u16* Kh   = (u16*)(p + 2 * H16);  u16* Kl   = (u16*)(p + 3 * H16);
  u16* KTh  = (u16*)(p + 4 * H16);  u16* KTl  = (u16*)(p + 5 * H16);
  u16* VdTh = (u16*)(p + 6 * H16);  u16* VdTl = (u16*)(p + 7 * H16);
  u16* VwTh = (u16*)(p + 8 * H16);  u16* VwTl = (u16*)(p + 9 * H16);
  u16* Sgh  = (u16*)(p + 10 * H16); u16* Sgl  = (u16*)(p + 11 * H16);
  u16* cMh  = (u16*)(p + 12 * H16); u16* cMl  = (u16*)(p + 13 * H16);
  float* lMatT = (float*)(p + 14 * H16);                 // 16 MB (14..16)
  float* VT32  = (float*)(p + 16 * H16);                 // 16 MB (16..18)
  u16* Wth = (u16*)(p + 18 * H16);
  u16* Wtl = (u16*)(p + 18 * H16 + 3 * DD * DD * 2);
  float* lVec = (float*)(p + 18 * H16 + 6 * DD * DD * 2);
  float* cVec = lVec + (size_t)BB * NCH * DD;
  // X-split aliases Sg/cM/lMat (dead until scores/lmat run, after proj)
  u16* Xh = (u16*)(p + 10 * H16);   // 24 MB: covers Sgh,Sgl,cMh
  u16* Xl = (u16*)(p + 13 * H16);   // 24 MB: covers cMl,lMatT

  packW_kernel<<<dim3(3, 2), 256, 0, stream>>>(Wq, Wk, Wv, Wth, Wtl);
  splitX_kernel<<<dim3(128, 3), 256, 0, stream>>>(xq, xk, xv, Xh, Xl);
  proj_kernel<<<dim3(BB * SS / 128, 2, 3), 256, 0, stream>>>(
      Xh, Xl, Wth, Wtl, bq, bk, bv, Qh, Ql, Kh, Kl, KTh, KTl, VT32);
  local_vec_kernel<<<BB * NCH, 256, 0, stream>>>(KTh, KTl, lVec);
  combine_vec_kernel<<<BB, 256, 0, stream>>>(lVec, cVec);
  scores_kernel<<<dim3(BB * NCH, 3), 256, 0, stream>>>(Qh, Ql, Kh, Kl, Sgh, Sgl);
  denom_vscale_kernel<<<128, 256, 0, stream>>>(
      Sgh, Sgl, Qh, Ql, cVec, VT32, VdTh, VdTl, VwTh, VwTl);
  lmat_kernel<<<dim3(BB * NCH, 4), 256, 0, stream>>>(VwTh, VwTl, KTh, KTl, lMatT);
  combine_mat_kernel<<<128, 256, 0, stream>>>(lMatT, cMh, cMl);
  out_kernel<<<dim3(BB * NCH, 4), 256, 0, stream>>>(
      Qh, Ql, cMh, cMl, Sgh, Sgl, VdTh, VdTl, out);
}

// Round 6
// 251.151 us; speedup vs baseline: 1.0410x; 1.0410x over previous
//
#include <hip/hip_runtime.h>
#include <math.h>

// Retention (B=4, S=4096, D=256): chunkwise, split-bf16 MFMA, packed k8-slab
// operands, async global->LDS staging, LDS-bounce coalesced epilogues,
// denom fused into scores via global rsP atomics.
#define BB 4
#define SS 4096
#define DD 256
#define LL 256
#define NCH 16
#define GAMMA 0.9865f
#define LOG2G (-0.019609034f)   // log2(0.9865)
#define INV1MG 74.07407407f     // 1/(1-gamma)
#define SLAB 1040               // padded LDS slab stride in u16 (2080 B)

typedef __attribute__((ext_vector_type(8))) short short8;
typedef __attribute__((ext_vector_type(4))) float f32x4;
typedef unsigned short u16;
typedef unsigned int u32;

__device__ __forceinline__ u16 f2bf(float f) {
  union { float f; unsigned u; } v; v.f = f;
  unsigned r = v.u + 0x7FFFu + ((v.u >> 16) & 1u);
  return (u16)(r >> 16);
}
__device__ __forceinline__ float bf2f(u16 h) {
  union { unsigned u; float f; } v; v.u = ((unsigned)h) << 16; return v.f;
}

__device__ __forceinline__ void gll16(const u16* g, u16* l) {
  __builtin_amdgcn_global_load_lds(
      (const __attribute__((address_space(1))) u32*)g,
      (__attribute__((address_space(3))) u32*)l, 16, 0, 0);
}
__device__ __forceinline__ void stage8kp(const u16* g, u16* l, int lane) {
#pragma unroll
  for (int i = 0; i < 8; ++i)
    gll16(g + i * 512 + lane * 8, l + (i >> 1) * SLAB + (i & 1) * 512);
}

__device__ __forceinline__ void mfma_step_slab(
    const u16* Ah, const u16* Al, const u16* Bh, const u16* Bl,
    int wm0, int wn0, int fm, int fq, f32x4 acc[4][4])
{
  const int ka = fq * SLAB;
  short8 ah[4], al[4];
#pragma unroll
  for (int i = 0; i < 4; ++i) {
    ah[i] = *(const short8*)&Ah[ka + (wm0 + i * 16 + fm) * 8];
    al[i] = *(const short8*)&Al[ka + (wm0 + i * 16 + fm) * 8];
  }
#pragma unroll
  for (int j = 0; j < 4; ++j) {
    short8 bh = *(const short8*)&Bh[ka + (wn0 + j * 16 + fm) * 8];
    short8 bl = *(const short8*)&Bl[ka + (wn0 + j * 16 + fm) * 8];
#pragma unroll
    for (int i = 0; i < 4; ++i) {
      acc[i][j] = __builtin_amdgcn_mfma_f32_16x16x32_bf16(al[i], bh, acc[i][j], 0, 0, 0);
      acc[i][j] = __builtin_amdgcn_mfma_f32_16x16x32_bf16(ah[i], bl, acc[i][j], 0, 0, 0);
      acc[i][j] = __builtin_amdgcn_mfma_f32_16x16x32_bf16(ah[i], bh, acc[i][j], 0, 0, 0);
    }
  }
}

// write this pass's column-half of acc into the fp32 bounce tile [128][65]
__device__ __forceinline__ void bounce_write(
    float* fb, const f32x4 acc[4][4], int wm0, int wn0, int fm, int fq, int p)
{
  if (wn0 == p * 64) {
#pragma unroll
    for (int i = 0; i < 4; ++i)
#pragma unroll
      for (int j = 0; j < 4; ++j)
#pragma unroll
        for (int r = 0; r < 4; ++r)
          fb[(wm0 + i * 16 + fq * 4 + r) * 65 + j * 16 + fm] = acc[i][j][r];
  }
}

// ---------------------------------------------------------------------------
// 0a) pack W^T into dense slab layout, split hi/lo
__global__ __launch_bounds__(256) void packW_kernel(
    const float* __restrict__ Wq, const float* __restrict__ Wk, const float* __restrict__ Wv,
    u16* __restrict__ Wth, u16* __restrict__ Wtl)
{
  const int which = blockIdx.x, pn = blockIdx.y;
  const float* W = which == 0 ? Wq : (which == 1 ? Wk : Wv);
  const int t = threadIdx.x;
  for (int it = 0; it < 16; ++it) {
    int pos = it * 256 + t;
    int k8 = pos >> 7, r = pos & 127;
    u16 hs[8], ls[8];
#pragma unroll
    for (int u = 0; u < 8; ++u) {
      float x = W[(size_t)(k8 * 8 + u) * DD + pn * 128 + r];
      u16 h = f2bf(x); hs[u] = h; ls[u] = f2bf(x - bf2f(h));
    }
    size_t o = ((size_t)((which * 2 + pn) * 32 + k8)) * 1024 + (size_t)r * 8;
    *(short8*)&Wth[o] = *(short8*)hs;
    *(short8*)&Wtl[o] = *(short8*)ls;
  }
}

// 0b) split X into packed slab hi/lo; also zero rsP (which==0 blocks)
__global__ __launch_bounds__(256) void splitX_kernel(
    const float* __restrict__ xq, const float* __restrict__ xk, const float* __restrict__ xv,
    u16* __restrict__ Xh, u16* __restrict__ Xl, float* __restrict__ rsP)
{
  const int panel = blockIdx.x, which = blockIdx.y;
  const float* X = which == 0 ? xq : (which == 1 ? xk : xv);
  __shared__ float tile[64][132];
  const int t = threadIdx.x;
  if (which == 0 && t < 128) rsP[(size_t)panel * 128 + t] = 0.f;
  const size_t rbase = (size_t)panel * 128 * DD;
  const size_t obase = (size_t)(which * 128 + panel) * 32768;
  for (int q = 0; q < 4; ++q) {
    int rh = q >> 1, kh = q & 1;
    __syncthreads();
#pragma unroll
    for (int v = 0; v < 8; ++v) {
      int lin = v * 256 + t;
      int col4 = lin & 31, row = lin >> 5;
      float4 x = *(const float4*)&X[rbase + (size_t)(rh * 64 + row) * DD + kh * 128 + col4 * 4];
      *(float4*)&tile[row][col4 * 4] = x;
    }
    __syncthreads();
#pragma unroll
    for (int it = 0; it < 4; ++it) {
      int unit = it * 256 + t;
      int sl = unit >> 6, row = unit & 63;
      u16 hs[8], ls[8];
#pragma unroll
      for (int u = 0; u < 8; ++u) {
        float x = tile[row][sl * 8 + u];
        u16 h = f2bf(x); hs[u] = h; ls[u] = f2bf(x - bf2f(h));
      }
      size_t o = obase + (size_t)(kh * 16 + sl) * 1024 + (size_t)(rh * 64 + row) * 8;
      *(short8*)&Xh[o] = *(short8*)hs;
      *(short8*)&Xl[o] = *(short8*)ls;
    }
  }
}

// ---------------------------------------------------------------------------
// 1) projections: Q~=(xWq+b)/16, K~=(xWk+b)/sqrt(c), V. Bounce epilogue.
__global__ __launch_bounds__(256, 3) void proj_kernel(
    const u16* __restrict__ Xh, const u16* __restrict__ Xl,
    const u16* __restrict__ Wth, const u16* __restrict__ Wtl,
    const float* __restrict__ bq, const float* __restrict__ bk_, const float* __restrict__ bv,
    u16* __restrict__ Qh, u16* __restrict__ Ql,
    u16* __restrict__ Kh, u16* __restrict__ Kl,
    u16* __restrict__ KTh, u16* __restrict__ KTl, float* __restrict__ VT32)
{
  const int which = blockIdx.z;
  const float* bias = which == 0 ? bq : (which == 1 ? bk_ : bv);
  const int m0 = blockIdx.x * 128;
  const int pn = blockIdx.y;
  __shared__ u16 SM[4 * 4 * SLAB];
  __shared__ float rsc[128];
  float* fb = (float*)SM;
  u16* Ah = SM; u16* Al = SM + 4 * SLAB; u16* Bh = SM + 8 * SLAB; u16* Bl = SM + 12 * SLAB;
  const int tid = threadIdx.x, lane = tid & 63, wave = tid >> 6;
  const int wm0 = (wave >> 1) * 64, wn0 = (wave & 1) * 64;
  const int fm = lane & 15, fq = lane >> 4;
  if (which == 1 && tid < 128) {
    int sb = (m0 & (SS - 1)) + tid;
    rsc[tid] = rsqrtf((1.0f - exp2f((float)(sb + 1) * LOG2G)) * INV1MG);
  }
  const u16* XhP = Xh + (size_t)(which * 128 + (m0 >> 7)) * 32768;
  const u16* XlP = Xl + (size_t)(which * 128 + (m0 >> 7)) * 32768;
  const u16* WhP = Wth + (size_t)((which * 2 + pn) * 32) * 1024;
  const u16* WlP = Wtl + (size_t)((which * 2 + pn) * 32) * 1024;
  f32x4 acc[4][4];
#pragma unroll
  for (int i = 0; i < 4; ++i)
#pragma unroll
    for (int j = 0; j < 4; ++j) acc[i][j] = (f32x4){0.f, 0.f, 0.f, 0.f};
  for (int ks = 0; ks < 8; ++ks) {
    __syncthreads();
    if (wave == 0) stage8kp(XhP + ks * 4096, Ah, lane);
    if (wave == 1) stage8kp(XlP + ks * 4096, Al, lane);
    if (wave == 2) stage8kp(WhP + ks * 4096, Bh, lane);
    if (wave == 3) stage8kp(WlP + ks * 4096, Bl, lane);
    __syncthreads();
    mfma_step_slab(Ah, Al, Bh, Bl, wm0, wn0, fm, fq, acc);
  }
  const int b = m0 >> 12, sbb = m0 & (SS - 1);
  for (int p = 0; p < 2; ++p) {
    __syncthreads();
    bounce_write(fb, acc, wm0, wn0, fm, fq, p);
    __syncthreads();
    if (which == 0) {
#pragma unroll
      for (int it = 0; it < 4; ++it) {
        int unit = it * 256 + tid;
        int k8l = unit >> 7, row = unit & 127;
        int gcol0 = pn * 128 + p * 64 + k8l * 8;
        u16 hs[8], ls[8];
#pragma unroll
        for (int u = 0; u < 8; ++u) {
          float v = (fb[row * 65 + k8l * 8 + u] + bias[gcol0 + u]) * (1.f / 16.f);
          u16 h = f2bf(v); hs[u] = h; ls[u] = f2bf(v - bf2f(h));
        }
        size_t o = (size_t)(m0 >> 7) * 32768 + (size_t)(pn * 16 + p * 8 + k8l) * 1024 + row * 8;
        *(short8*)&Qh[o] = *(short8*)hs;
        *(short8*)&Ql[o] = *(short8*)ls;
      }
    } else if (which == 1) {
#pragma unroll
      for (int it = 0; it < 4; ++it) {
        int unit = it * 256 + tid;
        int k8l = unit >> 7, row = unit & 127;
        int gcol0 = pn * 128 + p * 64 + k8l * 8;
        u16 hs[8], ls[8];
#pragma unroll
        for (int u = 0; u < 8; ++u) {
          float v = (fb[row * 65 + k8l * 8 + u] + bias[gcol0 + u]) * rsc[row];
          u16 h = f2bf(v); hs[u] = h; ls[u] = f2bf(v - bf2f(h));
        }
        size_t o = (size_t)(m0 >> 7) * 32768 + (size_t)(pn * 16 + p * 8 + k8l) * 1024 + row * 8;
        *(short8*)&Kh[o] = *(short8*)hs;
        *(short8*)&Kl[o] = *(short8*)ls;
      }
#pragma unroll
      for (int it = 0; it < 4; ++it) {
        int unit = it * 256 + tid;
        int dl = unit & 63, s8l = unit >> 6;
        int gcolg = pn * 128 + p * 64 + dl;
        float bs = bias[gcolg];
        u16 hs[8], ls[8];
#pragma unroll
        for (int u = 0; u < 8; ++u) {
          int row = s8l * 8 + u;
          float v = (fb[row * 65 + dl] + bs) * rsc[row];
          u16 h = f2bf(v); hs[u] = h; ls[u] = f2bf(v - bf2f(h));
        }
        int sb0 = sbb + s8l * 8;
        size_t o = ((size_t)(b * 2 + (gcolg >> 7)) * 512 + (sb0 >> 3)) * 1024 + (size_t)(gcolg & 127) * 8;
        *(short8*)&KTh[o] = *(short8*)hs;
        *(short8*)&KTl[o] = *(short8*)ls;
      }
    } else {
#pragma unroll
      for (int it = 0; it < 4; ++it) {
        int unit = it * 256 + tid;
        int dl = unit & 63, s8l = unit >> 6;
        int gcolg = pn * 128 + p * 64 + dl;
        float bs = bias[gcolg];
        float vv[8];
#pragma unroll
        for (int u = 0; u < 8; ++u) vv[u] = fb[(s8l * 8 + u) * 65 + dl] + bs;
        float* dst = &VT32[(size_t)b * DD * SS + (size_t)gcolg * SS + sbb + s8l * 8];
        *(float4*)dst = (float4){vv[0], vv[1], vv[2], vv[3]};
        *(float4*)(dst + 4) = (float4){vv[4], vv[5], vv[6], vv[7]};
      }
    }
  }
}

// ---------------------------------------------------------------------------
// 2) per-chunk vector state + carry scan
__global__ __launch_bounds__(256) void local_vec_kernel(
    const u16* __restrict__ KTh, const u16* __restrict__ KTl, float* __restrict__ lVec)
{
  const int chunk = blockIdx.x, b = chunk >> 4, c = chunk & 15;
  const int t = threadIdx.x;
  __shared__ float wt[256];
  wt[t] = exp2f((float)(255 - t) * LOG2G);
  __syncthreads();
  const int pd = t >> 7, dl = t & 127;
  float s = 0.f;
  for (int k8 = 0; k8 < 32; ++k8) {
    size_t o = ((size_t)((b * 2 + pd) * 512 + c * 32 + k8)) * 1024 + dl * 8;
    short8 hv = *(const short8*)&KTh[o];
    short8 lv = *(const short8*)&KTl[o];
#pragma unroll
    for (int u = 0; u < 8; ++u)
      s = fmaf(bf2f((u16)hv[u]) + bf2f((u16)lv[u]), wt[k8 * 8 + u], s);
  }
  lVec[(size_t)chunk * DD + t] = s;
}

__global__ __launch_bounds__(256) void combine_vec_kernel(
    const float* __restrict__ lVec, float* __restrict__ cVec)
{
  const int b = blockIdx.x;
  const int d = threadIdx.x;
  const float gL = powf(GAMMA, (float)LL);
  float s = 0.f;
  for (int c = 0; c < NCH; ++c) {
    cVec[(size_t)(b * NCH + c) * DD + d] = s;
    s = gL * s + lVec[(size_t)(b * NCH + c) * DD + d];
  }
}

// ---------------------------------------------------------------------------
// 3) Sg = mask*(Q~.K~)*g^(il-jl); fused rowsum + Q.cVec dot -> rsP atomics
__global__ __launch_bounds__(256, 3) void scores_kernel(
    const u16* __restrict__ Qh, const u16* __restrict__ Ql,
    const u16* __restrict__ Kh, const u16* __restrict__ Kl,
    const float* __restrict__ cVec, u16* __restrict__ Sgh, u16* __restrict__ Sgl,
    float* __restrict__ rsP)
{
  const int chunk = blockIdx.x, b = chunk >> 4, c = chunk & 15;
  const int ty = blockIdx.y;
  const int m0 = (ty == 0) ? 0 : 128;
  const int n0 = (ty == 2) ? 128 : 0;
  __shared__ u16 SM[4 * 4 * SLAB];
  __shared__ float cv[256], lut[256], rowAcc[128], qd2[2][128];
  float* fb = (float*)SM;
  u16* Ah = SM; u16* Al = SM + 4 * SLAB; u16* Bh = SM + 8 * SLAB; u16* Bl = SM + 12 * SLAB;
  const int tid = threadIdx.x, lane = tid & 63, wave = tid >> 6;
  const int wm0 = (wave >> 1) * 64, wn0 = (wave & 1) * 64;
  const int fm = lane & 15, fq = lane >> 4;
  cv[tid] = cVec[(size_t)(b * NCH + c) * DD + tid];
  lut[tid] = exp2f((float)tid * LOG2G);
  if (tid < 128) rowAcc[tid] = 0.f;
  const u16* QhP = Qh + (size_t)((b * SS + c * LL + m0) >> 7) * 32768;
  const u16* QlP = Ql + (size_t)((b * SS + c * LL + m0) >> 7) * 32768;
  const u16* KhP = Kh + (size_t)((b * SS + c * LL + n0) >> 7) * 32768;
  const u16* KlP = Kl + (size_t)((b * SS + c * LL + n0) >> 7) * 32768;
  f32x4 acc[4][4];
#pragma unroll
  for (int i = 0; i < 4; ++i)
#pragma unroll
    for (int j = 0; j < 4; ++j) acc[i][j] = (f32x4){0.f, 0.f, 0.f, 0.f};
  float qdreg = 0.f;
  const int qrow = tid & 127, qk8b = tid >> 7;
  for (int ks = 0; ks < 8; ++ks) {
    __syncthreads();
    if (wave == 0) stage8kp(QhP + ks * 4096, Ah, lane);
    if (wave == 1) stage8kp(QlP + ks * 4096, Al, lane);
    if (wave == 2) stage8kp(KhP + ks * 4096, Bh, lane);
    if (wave == 3) stage8kp(KlP + ks * 4096, Bl, lane);
    __syncthreads();
    mfma_step_slab(Ah, Al, Bh, Bl, wm0, wn0, fm, fq, acc);
    if (n0 == 0) {
#pragma unroll
      for (int h2 = 0; h2 < 2; ++h2) {
        int k8l = qk8b + 2 * h2;
        const u16* ahp = &Ah[k8l * SLAB + qrow * 8];
        const u16* alp = &Al[k8l * SLAB + qrow * 8];
#pragma unroll
        for (int u = 0; u < 8; ++u)
          qdreg = fmaf(bf2f(ahp[u]) + bf2f(alp[u]), cv[ks * 32 + k8l * 8 + u], qdreg);
      }
    }
  }
  qd2[qk8b][qrow] = qdreg;
  const int ps = chunk * 2 + (m0 >> 7);
  for (int p = 0; p < 2; ++p) {
    __syncthreads();
    bounce_write(fb, acc, wm0, wn0, fm, fq, p);
    __syncthreads();
#pragma unroll
    for (int it = 0; it < 4; ++it) {
      int unit = it * 256 + tid;
      int k8l = unit >> 7, row = unit & 127;
      int il = m0 + row;
      int jlb = n0 + p * 64 + k8l * 8;
      float part = 0.f;
      u16 hs[8], ls[8];
#pragma unroll
      for (int u = 0; u < 8; ++u) {
        int jl = jlb + u;
        float v = (jl <= il) ? fb[row * 65 + k8l * 8 + u] * lut[il - jl] : 0.f;
        part += v;
        u16 h = f2bf(v); hs[u] = h; ls[u] = f2bf(v - bf2f(h));
      }
      atomicAdd(&rowAcc[row], part);
      size_t o = (size_t)(ps * 32 + (n0 >> 3) + p * 8 + k8l) * 1024 + row * 8;
      *(short8*)&Sgh[o] = *(short8*)hs;
      *(short8*)&Sgl[o] = *(short8*)ls;
    }
  }
  __syncthreads();
  if (tid < 128) {
    float rs = rowAcc[tid];
    if (n0 == 0)
      rs += exp2f((float)(m0 + tid + 1) * LOG2G) * (qd2[0][tid] + qd2[1][tid]);
    atomicAdd(&rsP[(size_t)b * SS + c * LL + m0 + tid], rs);
  }
}

// ---------------------------------------------------------------------------
// 4) vscale: denom = max(|rsP|,1); Vd^T = V^T/denom, Vw^T = Vd^T * g^(L-1-jl)
__global__ __launch_bounds__(256) void vscale_kernel(
    const float* __restrict__ VT32, const float* __restrict__ rsP,
    u16* __restrict__ VdTh, u16* __restrict__ VdTl,
    u16* __restrict__ VwTh, u16* __restrict__ VwTl)
{
  const int x = blockIdx.x;  // 256: b(4) x pd(2) x sg(32)
  const int b = x >> 6, pd = (x >> 5) & 1, sg = x & 31;
  const int t = threadIdx.x;
  __shared__ float tile[64][132];
  __shared__ float sdn[128], wtl[128];
  if (t < 128) {
    int s = sg * 128 + t;
    sdn[t] = fmaxf(fabsf(rsP[(size_t)b * SS + s]), 1.0f);
    wtl[t] = exp2f((float)(255 - (s & 255)) * LOG2G);
  }
  for (int eh = 0; eh < 2; ++eh) {      // two 64-row e groups within this panel
    __syncthreads();
#pragma unroll
    for (int v = 0; v < 8; ++v) {       // load 64 e-rows x 128 s-cols
      int lin = v * 256 + t;
      int col4 = lin & 31, row = lin >> 5;
      float4 xv = *(const float4*)&VT32[(size_t)b * DD * SS +
          (size_t)(pd * 128 + eh * 64 + row) * SS + sg * 128 + col4 * 4];
      *(float4*)&tile[row][col4 * 4] = xv;
    }
    __syncthreads();
#pragma unroll
    for (int it = 0; it < 4; ++it) {    // 16 s8-chunks x 64 e-rows
      int unit = it * 256 + t;
      int s8l = unit >> 6, el = unit & 63;
      int e = pd * 128 + eh * 64 + el;
      u16 dh[8], dl_[8], wh[8], wl[8];
#pragma unroll
      for (int u = 0; u < 8; ++u) {
        int sloc = s8l * 8 + u;
        float vd = tile[el][sloc] / sdn[sloc];
        float vw = vd * wtl[sloc];
        u16 h = f2bf(vd); dh[u] = h; dl_[u] = f2bf(vd - bf2f(h));
        u16 h2 = f2bf(vw); wh[u] = h2; wl[u] = f2bf(vw - bf2f(h2));
      }
      int s8g = sg * 16 + s8l;
      size_t o = ((size_t)((b * 2 + pd) * 512 + s8g)) * 1024 + (size_t)(e & 127) * 8;
      *(short8*)&VdTh[o] = *(short8*)dh; *(short8*)&VdTl[o] = *(short8*)dl_;
      *(short8*)&VwTh[o] = *(short8*)wh; *(short8*)&VwTl[o] = *(short8*)wl;
    }
  }
}

// ---------------------------------------------------------------------------
// 5) lMatT[e][d] = sum_jl Vw[jl,e] K~[jl,d]
__global__ __launch_bounds__(256, 3) void lmat_kernel(
    const u16* __restrict__ VwTh, const u16* __restrict__ VwTl,
    const u16* __restrict__ KTh, const u16* __restrict__ KTl,
    float* __restrict__ lMatT)
{
  const int chunk = blockIdx.x, b = chunk >> 4, c = chunk & 15;
  const int ty = blockIdx.y;
  const int m0 = (ty >> 1) * 128, n0 = (ty & 1) * 128;
  __shared__ u16 SM[4 * 4 * SLAB];
  u16* Ah = SM; u16* Al = SM + 4 * SLAB; u16* Bh = SM + 8 * SLAB; u16* Bl = SM + 12 * SLAB;
  const int tid = threadIdx.x, lane = tid & 63, wave = tid >> 6;
  const int wm0 = (wave >> 1) * 64, wn0 = (wave & 1) * 64;
  const int fm = lane & 15, fq = lane >> 4;
  const u16* AhP = VwTh + ((size_t)(b * 2 + (m0 >> 7)) * 512 + c * 32) * 1024;
  const u16* AlP = VwTl + ((size_t)(b * 2 + (m0 >> 7)) * 512 + c * 32) * 1024;
  const u16* BhP = KTh + ((size_t)(b * 2 + (n0 >> 7)) * 512 + c * 32) * 1024;
  const u16* BlP = KTl + ((size_t)(b * 2 + (n0 >> 7)) * 512 + c * 32) * 1024;
  f32x4 acc[4][4];
#pragma unroll
  for (int i = 0; i < 4; ++i)
#pragma unroll
    for (int j = 0; j < 4; ++j) acc[i][j] = (f32x4){0.f, 0.f, 0.f, 0.f};
  for (int ks = 0; ks < 8; ++ks) {
    __syncthreads();
    if (wave == 0) stage8kp(AhP + ks * 4096, Ah, lane);
    if (wave == 1) stage8kp(AlP + ks * 4096, Al, lane);
    if (wave == 2) stage8kp(BhP + ks * 4096, Bh, lane);
    if (wave == 3) stage8kp(BlP + ks * 4096, Bl, lane);
    __syncthreads();
    mfma_step_slab(Ah, Al, Bh, Bl, wm0, wn0, fm, fq, acc);
  }
#pragma unroll
  for (int i = 0; i < 4; ++i)
#pragma unroll
    for (int j = 0; j < 4; ++j)
#pragma unroll
      for (int r = 0; r < 4; ++r) {
        int e = m0 + wm0 + i * 16 + fq * 4 + r;
        int d = n0 + wn0 + j * 16 + fm;
        lMatT[(size_t)chunk * 65536 + (size_t)e * 256 + d] = acc[i][j][r];
      }
}

// 6) carry scan -> cM packed split
__global__ __launch_bounds__(256) void combine_mat_kernel(
    const float* __restrict__ lMatT, u16* __restrict__ cMh, u16* __restrict__ cMl)
{
  const int t = blockIdx.x * 256 + threadIdx.x;
  const int b = t >> 13, rem = t & 8191;
  const int k8 = rem >> 8, e = rem & 255;
  const float gL = powf(GAMMA, (float)LL);
  float s[8] = {0.f, 0.f, 0.f, 0.f, 0.f, 0.f, 0.f, 0.f};
  for (int ch = 0; ch < 16; ++ch) {
    size_t ro = (size_t)(b * 16 + ch) * 65536 + (size_t)e * 256 + k8 * 8;
    float4 a0 = *(const float4*)&lMatT[ro];
    float4 a1 = *(const float4*)&lMatT[ro + 4];
    float vals[8] = {a0.x, a0.y, a0.z, a0.w, a1.x, a1.y, a1.z, a1.w};
    u16 hh[8], ll[8];
#pragma unroll
    for (int u = 0; u < 8; ++u) {
      u16 h = f2bf(s[u]); hh[u] = h; ll[u] = f2bf(s[u] - bf2f(h));
    }
    size_t wo = ((size_t)(((b * 16 + ch) * 2 + (e >> 7)) * 32 + k8)) * 1024 + (size_t)(e & 127) * 8;
    *(short8*)&cMh[wo] = *(short8*)hh;
    *(short8*)&cMl[wo] = *(short8*)ll;
#pragma unroll
    for (int u = 0; u < 8; ++u) s[u] = gL * s[u] + vals[u];
  }
}

// ---------------------------------------------------------------------------
// 7) out = g^(il+1) * Q~ @ cM^T + Sg @ Vd
__global__ __launch_bounds__(256, 3) void out_kernel(
    const u16* __restrict__ Qh, const u16* __restrict__ Ql,
    const u16* __restrict__ cMh, const u16* __restrict__ cMl,
    const u16* __restrict__ Sgh, const u16* __restrict__ Sgl,
    const u16* __restrict__ VdTh, const u16* __restrict__ VdTl,
    float* __restrict__ out)
{
  const int chunk = blockIdx.x, b = chunk >> 4, c = chunk & 15;
  const int ty = blockIdx.y;
  const int m0 = (ty >> 1) * 128, n0 = (ty & 1) * 128;
  __shared__ u16 SM[4 * 4 * SLAB];
  __shared__ float olut[128];
  u16* Ah = SM; u16* Al = SM + 4 * SLAB; u16* Bh = SM + 8 * SLAB; u16* Bl = SM + 12 * SLAB;
  const int tid = threadIdx.x, lane = tid & 63, wave = tid >> 6;
  const int wm0 = (wave >> 1) * 64, wn0 = (wave & 1) * 64;
  const int fm = lane & 15, fq = lane >> 4;
  if (tid < 128) olut[tid] = exp2f((float)(m0 + tid + 1) * LOG2G);
  f32x4 acc[4][4];
#pragma unroll
  for (int i = 0; i < 4; ++i)
#pragma unroll
    for (int j = 0; j < 4; ++j) acc[i][j] = (f32x4){0.f, 0.f, 0.f, 0.f};
  {
    const u16* AhP = Qh + (size_t)(b * 32 + c * 2 + (m0 >> 7)) * 32768;
    const u16* AlP = Ql + (size_t)(b * 32 + c * 2 + (m0 >> 7)) * 32768;
    const u16* BhP = cMh + (size_t)(chunk * 2 + (n0 >> 7)) * 32768;
    const u16* BlP = cMl + (size_t)(chunk * 2 + (n0 >> 7)) * 32768;
    for (int ks = 0; ks < 8; ++ks) {
      __syncthreads();
      if (wave == 0) stage8kp(AhP + ks * 4096, Ah, lane);
      if (wave == 1) stage8kp(AlP + ks * 4096, Al, lane);
      if (wave == 2) stage8kp(BhP + ks * 4096, Bh, lane);
      if (wave == 3) stage8kp(BlP + ks * 4096, Bl, lane);
      __syncthreads();
      mfma_step_slab(Ah, Al, Bh, Bl, wm0, wn0, fm, fq, acc);
    }
  }
#pragma unroll
  for (int i = 0; i < 4; ++i)
#pragma unroll
    for (int r = 0; r < 4; ++r) {
      int rl = wm0 + i * 16 + fq * 4 + r;
      float sc = olut[rl];
#pragma unroll
      for (int j = 0; j < 4; ++j) acc[i][j][r] *= sc;
    }
  {
    const u16* AhP = Sgh + (size_t)(chunk * 2 + (m0 >> 7)) * 32768;
    const u16* AlP = Sgl + (size_t)(chunk * 2 + (m0 >> 7)) * 32768;
    const u16* BhP = VdTh + ((size_t)(b * 2 + (n0 >> 7)) * 512 + c * 32) * 1024;
    const u16* BlP = VdTl + ((size_t)(b * 2 + (n0 >> 7)) * 512 + c * 32) * 1024;
    const int nks = (m0 >> 5) + 4;
    for (int ks = 0; ks < nks; ++ks) {
      __syncthreads();
      if (wave == 0) stage8kp(AhP + ks * 4096, Ah, lane);
      if (wave == 1) stage8kp(AlP + ks * 4096, Al, lane);
      if (wave == 2) stage8kp(BhP + ks * 4096, Bh, lane);
      if (wave == 3) stage8kp(BlP + ks * 4096, Bl, lane);
      __syncthreads();
      mfma_step_slab(Ah, Al, Bh, Bl, wm0, wn0, fm, fq, acc);
    }
  }
#pragma unroll
  for (int i = 0; i < 4; ++i)
#pragma unroll
    for (int j = 0; j < 4; ++j)
#pragma unroll
      for (int r = 0; r < 4; ++r) {
        int il = m0 + wm0 + i * 16 + fq * 4 + r;
        int e = n0 + wn0 + j * 16 + fm;
        out[(size_t)(b * SS + c * LL + il) * DD + e] = acc[i][j][r];
      }
}

// ---------------------------------------------------------------------------
extern "C" void kernel_launch(void* const* d_in, const int* in_sizes, int n_in,
                              void* d_out, int out_size, void* d_ws, size_t ws_size,
                              hipStream_t stream) {
  const float* xq = (const float*)d_in[0];
  const float* xk = (const float*)d_in[1];
  const float* xv = (const float*)d_in[2];
  const float* Wq = (const float*)d_in[3];
  const float* bq = (const float*)d_in[4];
  const float* Wk = (const float*)d_in[5];
  const float* bk = (const float*)d_in[6];
  const float* Wv = (const float*)d_in[7];
  const float* bv = (const float*)d_in[8];
  float* out = (float*)d_out;

  char* p = (char*)d_ws;
  const size_t H16 = (size_t)BB * SS * DD * 2;  // 8 MB
  u16* Qh   = (u16*)(p + 0 * H16);  u16* Ql   = (u16*)(p + 1 * H16);
  u16* Kh   = (u16*)(p + 2 * H16);  u16* Kl   = (u16*)(p + 3 * H16);
  u16* KTh  = (u16*)(p + 4 * H16);  u16* KTl  = (u16*)(p + 5 * H16);
  u16* VdTh = (u16*)(p + 6 * H16);  u16* VdTl = (u16*)(p + 7 * H16);
  u16* VwTh = (u16*)(p + 8 * H16);  u16* VwTl = (u16*)(p + 9 * H16);
  u16* Sgh  = (u16*)(p + 10 * H16); u16* Sgl  = (u16*)(p + 11 * H16);
  u16* cMh  = (u16*)(p + 12 * H16); u16* cMl  = (u16*)(p + 13 * H16);
  float* lMatT = (float*)(p + 14 * H16);
  float* VT32  = (float*)(p + 16 * H16);
  u16* Wth = (u16*)(p + 18 * H16);
  u16* Wtl = (u16*)(p + 18 * H16 + 3 * DD * DD * 2);
  float* rsP  = (float*)(p + 18 * H16 + 6 * DD * DD * 2);
  float* lVec = rsP + (size_t)BB * SS;
  float* cVec = lVec + (size_t)BB * NCH * DD;
  u16* Xh = (u16*)(p + 10 * H16);
  u16* Xl = (u16*)(p + 13 * H16);

  packW_kernel<<<dim3(3, 2), 256, 0, stream>>>(Wq, Wk, Wv, Wth, Wtl);
  splitX_kernel<<<dim3(128, 3), 256, 0, stream>>>(xq, xk, xv, Xh, Xl, rsP);
  proj_kernel<<<dim3(BB * SS / 128, 2, 3), 256, 0, stream>>>(
      Xh, Xl, Wth, Wtl, bq, bk, bv, Qh, Ql, Kh, Kl, KTh, KTl, VT32);
  local_vec_kernel<<<BB * NCH, 256, 0, stream>>>(KTh, KTl, lVec);
  combine_vec_kernel<<<BB, 256, 0, stream>>>(lVec, cVec);
  scores_kernel<<<dim3(BB * NCH, 3), 256, 0, stream>>>(
      Qh, Ql, Kh, Kl, cVec, Sgh, Sgl, rsP);
  vscale_kernel<<<256, 256, 0, stream>>>(VT32, rsP, VdTh, VdTl, VwTh, VwTl);
  lmat_kernel<<<dim3(BB * NCH, 4), 256, 0, stream>>>(VwTh, VwTl, KTh, KTl, lMatT);
  combine_mat_kernel<<<128, 256, 0, stream>>>(lMatT, cMh, cMl);
  out_kernel<<<dim3(BB * NCH, 4), 256, 0, stream>>>(
      Qh, Ql, cMh, cMl, Sgh, Sgl, VdTh, VdTl, out);
}

// Round 7
// 240.516 us; speedup vs baseline: 1.0870x; 1.0442x over previous
//
#include <hip/hip_runtime.h>
#include <math.h>

// Retention (B=4, S=4096, D=256): chunkwise, split-bf16 MFMA, packed k8-slab
// operands, async global->LDS staging. Chunk GEMMs retiled to 128x64 blocks
// (2+ blocks/CU) so barrier-drain latency overlaps across blocks.
#define BB 4
#define SS 4096
#define DD 256
#define LL 256
#define NCH 16
#define GAMMA 0.9865f
#define LOG2G (-0.019609034f)   // log2(0.9865)
#define INV1MG 74.07407407f     // 1/(1-gamma)
#define SLAB 1040               // padded LDS slab stride (u16) for 128-row panels
#define SLABB 520               // padded LDS slab stride (u16) for 64-row panels

typedef __attribute__((ext_vector_type(8))) short short8;
typedef __attribute__((ext_vector_type(4))) float f32x4;
typedef unsigned short u16;
typedef unsigned int u32;

__device__ __forceinline__ u16 f2bf(float f) {
  union { float f; unsigned u; } v; v.f = f;
  unsigned r = v.u + 0x7FFFu + ((v.u >> 16) & 1u);
  return (u16)(r >> 16);
}
__device__ __forceinline__ float bf2f(u16 h) {
  union { unsigned u; float f; } v; v.u = ((unsigned)h) << 16; return v.f;
}

__device__ __forceinline__ void gll16(const u16* g, u16* l) {
  __builtin_amdgcn_global_load_lds(
      (const __attribute__((address_space(1))) u32*)g,
      (__attribute__((address_space(3))) u32*)l, 16, 0, 0);
}
// stage one BK=32 k-step of a 128-row panel (4 slabs) into padded LDS
__device__ __forceinline__ void stage8kp(const u16* g, u16* l, int lane) {
#pragma unroll
  for (int i = 0; i < 8; ++i)
    gll16(g + i * 512 + lane * 8, l + (i >> 1) * SLAB + (i & 1) * 512);
}
// stage one BK=32 k-step of 64 rows taken from 128-row slabs (row-offset folded
// into g by caller): 4 slabs x 64 rows
__device__ __forceinline__ void stageB64(const u16* g, u16* l, int lane) {
#pragma unroll
  for (int i = 0; i < 4; ++i)
    gll16(g + i * 1024 + lane * 8, l + i * SLABB);
}

// 128x128 tile (4 waves, 64x64 each), split-bf16 3-product — used by proj
__device__ __forceinline__ void mfma_step_slab(
    const u16* Ah, const u16* Al, const u16* Bh, const u16* Bl,
    int wm0, int wn0, int fm, int fq, f32x4 acc[4][4])
{
  const int ka = fq * SLAB;
  short8 ah[4], al[4];
#pragma unroll
  for (int i = 0; i < 4; ++i) {
    ah[i] = *(const short8*)&Ah[ka + (wm0 + i * 16 + fm) * 8];
    al[i] = *(const short8*)&Al[ka + (wm0 + i * 16 + fm) * 8];
  }
#pragma unroll
  for (int j = 0; j < 4; ++j) {
    short8 bh = *(const short8*)&Bh[ka + (wn0 + j * 16 + fm) * 8];
    short8 bl = *(const short8*)&Bl[ka + (wn0 + j * 16 + fm) * 8];
#pragma unroll
    for (int i = 0; i < 4; ++i) {
      acc[i][j] = __builtin_amdgcn_mfma_f32_16x16x32_bf16(al[i], bh, acc[i][j], 0, 0, 0);
      acc[i][j] = __builtin_amdgcn_mfma_f32_16x16x32_bf16(ah[i], bl, acc[i][j], 0, 0, 0);
      acc[i][j] = __builtin_amdgcn_mfma_f32_16x16x32_bf16(ah[i], bh, acc[i][j], 0, 0, 0);
    }
  }
}

// 128x64 tile (4 waves, 64x32 each), split-bf16 3-product
__device__ __forceinline__ void mfma_step_ab(
    const u16* Ah, const u16* Al, const u16* Bh, const u16* Bl,
    int wm0, int wn0, int fm, int fq, f32x4 acc[4][2])
{
  const int ka = fq * SLAB, kb = fq * SLABB;
  short8 ah[4], al[4];
#pragma unroll
  for (int i = 0; i < 4; ++i) {
    ah[i] = *(const short8*)&Ah[ka + (wm0 + i * 16 + fm) * 8];
    al[i] = *(const short8*)&Al[ka + (wm0 + i * 16 + fm) * 8];
  }
#pragma unroll
  for (int j = 0; j < 2; ++j) {
    short8 bh = *(const short8*)&Bh[kb + (wn0 + j * 16 + fm) * 8];
    short8 bl = *(const short8*)&Bl[kb + (wn0 + j * 16 + fm) * 8];
#pragma unroll
    for (int i = 0; i < 4; ++i) {
      acc[i][j] = __builtin_amdgcn_mfma_f32_16x16x32_bf16(al[i], bh, acc[i][j], 0, 0, 0);
      acc[i][j] = __builtin_amdgcn_mfma_f32_16x16x32_bf16(ah[i], bl, acc[i][j], 0, 0, 0);
      acc[i][j] = __builtin_amdgcn_mfma_f32_16x16x32_bf16(ah[i], bh, acc[i][j], 0, 0, 0);
    }
  }
}

// write this pass's column-half of a 128x128 acc into fp32 bounce tile [128][65]
__device__ __forceinline__ void bounce_write(
    float* fb, const f32x4 acc[4][4], int wm0, int wn0, int fm, int fq, int p)
{
  if (wn0 == p * 64) {
#pragma unroll
    for (int i = 0; i < 4; ++i)
#pragma unroll
      for (int j = 0; j < 4; ++j)
#pragma unroll
        for (int r = 0; r < 4; ++r)
          fb[(wm0 + i * 16 + fq * 4 + r) * 65 + j * 16 + fm] = acc[i][j][r];
  }
}

// ---------------------------------------------------------------------------
// 0) split X into packed slab hi/lo (+ zero rsP); blockIdx.x==128 -> pack W^T
__global__ __launch_bounds__(256) void splitXW_kernel(
    const float* __restrict__ xq, const float* __restrict__ xk, const float* __restrict__ xv,
    const float* __restrict__ Wq, const float* __restrict__ Wk, const float* __restrict__ Wv,
    u16* __restrict__ Xh, u16* __restrict__ Xl,
    u16* __restrict__ Wth, u16* __restrict__ Wtl, float* __restrict__ rsP)
{
  const int which = blockIdx.y;
  const int t = threadIdx.x;
  if (blockIdx.x == 128) {  // pack W^T for this `which`
    const float* W = which == 0 ? Wq : (which == 1 ? Wk : Wv);
    for (int pn = 0; pn < 2; ++pn) {
      for (int it = 0; it < 16; ++it) {
        int pos = it * 256 + t;
        int k8 = pos >> 7, r = pos & 127;
        u16 hs[8], ls[8];
#pragma unroll
        for (int u = 0; u < 8; ++u) {
          float x = W[(size_t)(k8 * 8 + u) * DD + pn * 128 + r];
          u16 h = f2bf(x); hs[u] = h; ls[u] = f2bf(x - bf2f(h));
        }
        size_t o = ((size_t)((which * 2 + pn) * 32 + k8)) * 1024 + (size_t)r * 8;
        *(short8*)&Wth[o] = *(short8*)hs;
        *(short8*)&Wtl[o] = *(short8*)ls;
      }
    }
    return;
  }
  const int panel = blockIdx.x;
  const float* X = which == 0 ? xq : (which == 1 ? xk : xv);
  __shared__ float tile[64][132];
  if (which == 0 && t < 128) rsP[(size_t)panel * 128 + t] = 0.f;
  const size_t rbase = (size_t)panel * 128 * DD;
  const size_t obase = (size_t)(which * 128 + panel) * 32768;
  for (int q = 0; q < 4; ++q) {
    int rh = q >> 1, kh = q & 1;
    __syncthreads();
#pragma unroll
    for (int v = 0; v < 8; ++v) {
      int lin = v * 256 + t;
      int col4 = lin & 31, row = lin >> 5;
      float4 x = *(const float4*)&X[rbase + (size_t)(rh * 64 + row) * DD + kh * 128 + col4 * 4];
      *(float4*)&tile[row][col4 * 4] = x;
    }
    __syncthreads();
#pragma unroll
    for (int it = 0; it < 4; ++it) {
      int unit = it * 256 + t;
      int sl = unit >> 6, row = unit & 63;
      u16 hs[8], ls[8];
#pragma unroll
      for (int u = 0; u < 8; ++u) {
        float x = tile[row][sl * 8 + u];
        u16 h = f2bf(x); hs[u] = h; ls[u] = f2bf(x - bf2f(h));
      }
      size_t o = obase + (size_t)(kh * 16 + sl) * 1024 + (size_t)(rh * 64 + row) * 8;
      *(short8*)&Xh[o] = *(short8*)hs;
      *(short8*)&Xl[o] = *(short8*)ls;
    }
  }
}

// ---------------------------------------------------------------------------
// 1) projections: Q~=(xWq+b)/16, K~=(xWk+b)/sqrt(c), V. Bounce epilogue.
__global__ __launch_bounds__(256, 3) void proj_kernel(
    const u16* __restrict__ Xh, const u16* __restrict__ Xl,
    const u16* __restrict__ Wth, const u16* __restrict__ Wtl,
    const float* __restrict__ bq, const float* __restrict__ bk_, const float* __restrict__ bv,
    u16* __restrict__ Qh, u16* __restrict__ Ql,
    u16* __restrict__ Kh, u16* __restrict__ Kl,
    u16* __restrict__ KTh, u16* __restrict__ KTl, float* __restrict__ VT32)
{
  const int which = blockIdx.z;
  const float* bias = which == 0 ? bq : (which == 1 ? bk_ : bv);
  const int m0 = blockIdx.x * 128;
  const int pn = blockIdx.y;
  __shared__ u16 SM[4 * 4 * SLAB];
  __shared__ float rsc[128];
  float* fb = (float*)SM;
  u16* Ah = SM; u16* Al = SM + 4 * SLAB; u16* Bh = SM + 8 * SLAB; u16* Bl = SM + 12 * SLAB;
  const int tid = threadIdx.x, lane = tid & 63, wave = tid >> 6;
  const int wm0 = (wave >> 1) * 64, wn0 = (wave & 1) * 64;
  const int fm = lane & 15, fq = lane >> 4;
  if (which == 1 && tid < 128) {
    int sb = (m0 & (SS - 1)) + tid;
    rsc[tid] = rsqrtf((1.0f - exp2f((float)(sb + 1) * LOG2G)) * INV1MG);
  }
  const u16* XhP = Xh + (size_t)(which * 128 + (m0 >> 7)) * 32768;
  const u16* XlP = Xl + (size_t)(which * 128 + (m0 >> 7)) * 32768;
  const u16* WhP = Wth + (size_t)((which * 2 + pn) * 32) * 1024;
  const u16* WlP = Wtl + (size_t)((which * 2 + pn) * 32) * 1024;
  f32x4 acc[4][4];
#pragma unroll
  for (int i = 0; i < 4; ++i)
#pragma unroll
    for (int j = 0; j < 4; ++j) acc[i][j] = (f32x4){0.f, 0.f, 0.f, 0.f};
  for (int ks = 0; ks < 8; ++ks) {
    __syncthreads();
    if (wave == 0) stage8kp(XhP + ks * 4096, Ah, lane);
    if (wave == 1) stage8kp(XlP + ks * 4096, Al, lane);
    if (wave == 2) stage8kp(WhP + ks * 4096, Bh, lane);
    if (wave == 3) stage8kp(WlP + ks * 4096, Bl, lane);
    __syncthreads();
    mfma_step_slab(Ah, Al, Bh, Bl, wm0, wn0, fm, fq, acc);
  }
  const int b = m0 >> 12, sbb = m0 & (SS - 1);
  for (int p = 0; p < 2; ++p) {
    __syncthreads();
    bounce_write(fb, acc, wm0, wn0, fm, fq, p);
    __syncthreads();
    if (which == 0) {
#pragma unroll
      for (int it = 0; it < 4; ++it) {
        int unit = it * 256 + tid;
        int k8l = unit >> 7, row = unit & 127;
        int gcol0 = pn * 128 + p * 64 + k8l * 8;
        u16 hs[8], ls[8];
#pragma unroll
        for (int u = 0; u < 8; ++u) {
          float v = (fb[row * 65 + k8l * 8 + u] + bias[gcol0 + u]) * (1.f / 16.f);
          u16 h = f2bf(v); hs[u] = h; ls[u] = f2bf(v - bf2f(h));
        }
        size_t o = (size_t)(m0 >> 7) * 32768 + (size_t)(pn * 16 + p * 8 + k8l) * 1024 + row * 8;
        *(short8*)&Qh[o] = *(short8*)hs;
        *(short8*)&Ql[o] = *(short8*)ls;
      }
    } else if (which == 1) {
#pragma unroll
      for (int it = 0; it < 4; ++it) {
        int unit = it * 256 + tid;
        int k8l = unit >> 7, row = unit & 127;
        int gcol0 = pn * 128 + p * 64 + k8l * 8;
        u16 hs[8], ls[8];
#pragma unroll
        for (int u = 0; u < 8; ++u) {
          float v = (fb[row * 65 + k8l * 8 + u] + bias[gcol0 + u]) * rsc[row];
          u16 h = f2bf(v); hs[u] = h; ls[u] = f2bf(v - bf2f(h));
        }
        size_t o = (size_t)(m0 >> 7) * 32768 + (size_t)(pn * 16 + p * 8 + k8l) * 1024 + row * 8;
        *(short8*)&Kh[o] = *(short8*)hs;
        *(short8*)&Kl[o] = *(short8*)ls;
      }
#pragma unroll
      for (int it = 0; it < 4; ++it) {
        int unit = it * 256 + tid;
        int dl = unit & 63, s8l = unit >> 6;
        int gcolg = pn * 128 + p * 64 + dl;
        float bs = bias[gcolg];
        u16 hs[8], ls[8];
#pragma unroll
        for (int u = 0; u < 8; ++u) {
          int row = s8l * 8 + u;
          float v = (fb[row * 65 + dl] + bs) * rsc[row];
          u16 h = f2bf(v); hs[u] = h; ls[u] = f2bf(v - bf2f(h));
        }
        int sb0 = sbb + s8l * 8;
        size_t o = ((size_t)(b * 2 + (gcolg >> 7)) * 512 + (sb0 >> 3)) * 1024 + (size_t)(gcolg & 127) * 8;
        *(short8*)&KTh[o] = *(short8*)hs;
        *(short8*)&KTl[o] = *(short8*)ls;
      }
    } else {
#pragma unroll
      for (int it = 0; it < 4; ++it) {
        int unit = it * 256 + tid;
        int dl = unit & 63, s8l = unit >> 6;
        int gcolg = pn * 128 + p * 64 + dl;
        float bs = bias[gcolg];
        float vv[8];
#pragma unroll
        for (int u = 0; u < 8; ++u) vv[u] = fb[(s8l * 8 + u) * 65 + dl] + bs;
        float* dst = &VT32[(size_t)b * DD * SS + (size_t)gcolg * SS + sbb + s8l * 8];
        *(float4*)dst = (float4){vv[0], vv[1], vv[2], vv[3]};
        *(float4*)(dst + 4) = (float4){vv[4], vv[5], vv[6], vv[7]};
      }
    }
  }
}

// ---------------------------------------------------------------------------
// 2) per-chunk vector state + carry scan
__global__ __launch_bounds__(256) void local_vec_kernel(
    const u16* __restrict__ KTh, const u16* __restrict__ KTl, float* __restrict__ lVec)
{
  const int chunk = blockIdx.x, b = chunk >> 4, c = chunk & 15;
  const int t = threadIdx.x;
  __shared__ float wt[256];
  wt[t] = exp2f((float)(255 - t) * LOG2G);
  __syncthreads();
  const int pd = t >> 7, dl = t & 127;
  float s = 0.f;
  for (int k8 = 0; k8 < 32; ++k8) {
    size_t o = ((size_t)((b * 2 + pd) * 512 + c * 32 + k8)) * 1024 + dl * 8;
    short8 hv = *(const short8*)&KTh[o];
    short8 lv = *(const short8*)&KTl[o];
#pragma unroll
    for (int u = 0; u < 8; ++u)
      s = fmaf(bf2f((u16)hv[u]) + bf2f((u16)lv[u]), wt[k8 * 8 + u], s);
  }
  lVec[(size_t)chunk * DD + t] = s;
}

__global__ __launch_bounds__(256) void combine_vec_kernel(
    const float* __restrict__ lVec, float* __restrict__ cVec)
{
  const int b = blockIdx.x;
  const int d = threadIdx.x;
  const float gL = powf(GAMMA, (float)LL);
  float s = 0.f;
  for (int c = 0; c < NCH; ++c) {
    cVec[(size_t)(b * NCH + c) * DD + d] = s;
    s = gL * s + lVec[(size_t)(b * NCH + c) * DD + d];
  }
}

// ---------------------------------------------------------------------------
// 3) Sg = mask*(Q~.K~)*g^(il-jl); fused rowsum + Q.cVec dot -> rsP atomics.
//    128x64 tiles: y<2 -> m0=0, jn0=y*64 ; y>=2 -> m0=128, jn0=(y-2)*64
__global__ __launch_bounds__(256, 3) void scores_kernel(
    const u16* __restrict__ Qh, const u16* __restrict__ Ql,
    const u16* __restrict__ Kh, const u16* __restrict__ Kl,
    const float* __restrict__ cVec, u16* __restrict__ Sgh, u16* __restrict__ Sgl,
    float* __restrict__ rsP)
{
  const int chunk = blockIdx.x, b = chunk >> 4, c = chunk & 15;
  const int y = blockIdx.y;
  const int m0 = (y < 2) ? 0 : 128;
  const int jn0 = (y < 2) ? y * 64 : (y - 2) * 64;
  __shared__ u16 SA[8 * SLAB];
  __shared__ u16 SB[8 * SLABB];
  __shared__ float cv[256], lut[256], rowAcc[128], qd2[2][128];
  u16* Ah = SA; u16* Al = SA + 4 * SLAB;
  u16* Bh = SB; u16* Bl = SB + 4 * SLABB;
  float* fb = (float*)SA;  // 64x65 fp32 = 16640 B = |SA|
  const int tid = threadIdx.x, lane = tid & 63, wave = tid >> 6;
  const int wm0 = (wave >> 1) * 64, wn0 = (wave & 1) * 32;
  const int fm = lane & 15, fq = lane >> 4;
  cv[tid] = cVec[(size_t)(b * NCH + c) * DD + tid];
  lut[tid] = exp2f((float)tid * LOG2G);
  if (tid < 128) rowAcc[tid] = 0.f;
  const int growA = b * SS + c * LL + m0;
  const int growB = b * SS + c * LL + jn0;
  const u16* QhP = Qh + (size_t)(growA >> 7) * 32768;
  const u16* QlP = Ql + (size_t)(growA >> 7) * 32768;
  const u16* KhP = Kh + (size_t)(growB >> 7) * 32768 + (size_t)(growB & 127) * 8;
  const u16* KlP = Kl + (size_t)(growB >> 7) * 32768 + (size_t)(growB & 127) * 8;
  f32x4 acc[4][2];
#pragma unroll
  for (int i = 0; i < 4; ++i)
#pragma unroll
    for (int j = 0; j < 2; ++j) acc[i][j] = (f32x4){0.f, 0.f, 0.f, 0.f};
  float qdreg = 0.f;
  const int qrow = tid & 127, qk8b = tid >> 7;
  for (int ks = 0; ks < 8; ++ks) {
    __syncthreads();
    if (wave == 0) stage8kp(QhP + ks * 4096, Ah, lane);
    if (wave == 1) stage8kp(QlP + ks * 4096, Al, lane);
    if (wave == 2) stageB64(KhP + ks * 4096, Bh, lane);
    if (wave == 3) stageB64(KlP + ks * 4096, Bl, lane);
    __syncthreads();
    mfma_step_ab(Ah, Al, Bh, Bl, wm0, wn0, fm, fq, acc);
    if (jn0 == 0) {
#pragma unroll
      for (int h2 = 0; h2 < 2; ++h2) {
        int k8l = qk8b + 2 * h2;
        const u16* ahp = &Ah[k8l * SLAB + qrow * 8];
        const u16* alp = &Al[k8l * SLAB + qrow * 8];
#pragma unroll
        for (int u = 0; u < 8; ++u)
          qdreg = fmaf(bf2f(ahp[u]) + bf2f(alp[u]), cv[ks * 32 + k8l * 8 + u], qdreg);
      }
    }
  }
  qd2[qk8b][qrow] = qdreg;
  const int ps = chunk * 2 + (m0 >> 7);
  for (int rh = 0; rh < 2; ++rh) {
    __syncthreads();
    if (wm0 == rh * 64) {
#pragma unroll
      for (int i = 0; i < 4; ++i)
#pragma unroll
        for (int j = 0; j < 2; ++j)
#pragma unroll
          for (int r = 0; r < 4; ++r)
            fb[(i * 16 + fq * 4 + r) * 65 + wn0 + j * 16 + fm] = acc[i][j][r];
    }
    __syncthreads();
#pragma unroll
    for (int it = 0; it < 2; ++it) {
      int unit = it * 256 + tid;          // 8 k8-cols x 64 rows
      int k8l = unit >> 6, rowl = unit & 63;
      int il = m0 + rh * 64 + rowl;
      int jlb = jn0 + k8l * 8;
      float part = 0.f;
      u16 hs[8], ls[8];
#pragma unroll
      for (int u = 0; u < 8; ++u) {
        int jl = jlb + u;
        float v = (jl <= il) ? fb[rowl * 65 + k8l * 8 + u] * lut[il - jl] : 0.f;
        part += v;
        u16 h = f2bf(v); hs[u] = h; ls[u] = f2bf(v - bf2f(h));
      }
      atomicAdd(&rowAcc[rh * 64 + rowl], part);
      size_t o = (size_t)(ps * 32 + (jn0 >> 3) + k8l) * 1024 + (size_t)(rh * 64 + rowl) * 8;
      *(short8*)&Sgh[o] = *(short8*)hs;
      *(short8*)&Sgl[o] = *(short8*)ls;
    }
  }
  __syncthreads();
  if (tid < 128) {
    float rs = rowAcc[tid];
    if (jn0 == 0)
      rs += exp2f((float)(m0 + tid + 1) * LOG2G) * (qd2[0][tid] + qd2[1][tid]);
    atomicAdd(&rsP[(size_t)b * SS + c * LL + m0 + tid], rs);
  }
}

// ---------------------------------------------------------------------------
// 4) vscale: denom = max(|rsP|,1); Vd^T = V^T/denom, Vw^T = Vd^T * g^(L-1-jl)
__global__ __launch_bounds__(256) void vscale_kernel(
    const float* __restrict__ VT32, const float* __restrict__ rsP,
    u16* __restrict__ VdTh, u16* __restrict__ VdTl,
    u16* __restrict__ VwTh, u16* __restrict__ VwTl)
{
  const int x = blockIdx.x;  // 256: b(4) x pd(2) x sg(32)
  const int b = x >> 6, pd = (x >> 5) & 1, sg = x & 31;
  const int t = threadIdx.x;
  __shared__ float tile[64][132];
  __shared__ float sdn[128], wtl[128];
  if (t < 128) {
    int s = sg * 128 + t;
    sdn[t] = fmaxf(fabsf(rsP[(size_t)b * SS + s]), 1.0f);
    wtl[t] = exp2f((float)(255 - (s & 255)) * LOG2G);
  }
  for (int eh = 0; eh < 2; ++eh) {
    __syncthreads();
#pragma unroll
    for (int v = 0; v < 8; ++v) {
      int lin = v * 256 + t;
      int col4 = lin & 31, row = lin >> 5;
      float4 xv = *(const float4*)&VT32[(size_t)b * DD * SS +
          (size_t)(pd * 128 + eh * 64 + row) * SS + sg * 128 + col4 * 4];
      *(float4*)&tile[row][col4 * 4] = xv;
    }
    __syncthreads();
#pragma unroll
    for (int it = 0; it < 4; ++it) {
      int unit = it * 256 + t;
      int s8l = unit >> 6, el = unit & 63;
      int e = pd * 128 + eh * 64 + el;
      u16 dh[8], dl_[8], wh[8], wl[8];
#pragma unroll
      for (int u = 0; u < 8; ++u) {
        int sloc = s8l * 8 + u;
        float vd = tile[el][sloc] / sdn[sloc];
        float vw = vd * wtl[sloc];
        u16 h = f2bf(vd); dh[u] = h; dl_[u] = f2bf(vd - bf2f(h));
        u16 h2 = f2bf(vw); wh[u] = h2; wl[u] = f2bf(vw - bf2f(h2));
      }
      int s8g = sg * 16 + s8l;
      size_t o = ((size_t)((b * 2 + pd) * 512 + s8g)) * 1024 + (size_t)(e & 127) * 8;
      *(short8*)&VdTh[o] = *(short8*)dh; *(short8*)&VdTl[o] = *(short8*)dl_;
      *(short8*)&VwTh[o] = *(short8*)wh; *(short8*)&VwTl[o] = *(short8*)wl;
    }
  }
}

// ---------------------------------------------------------------------------
// 5) lMatT[e][d] = sum_jl Vw[jl,e] K~[jl,d] ; 128x64 tiles (grid 64x8)
__global__ __launch_bounds__(256, 3) void lmat_kernel(
    const u16* __restrict__ VwTh, const u16* __restrict__ VwTl,
    const u16* __restrict__ KTh, const u16* __restrict__ KTl,
    float* __restrict__ lMatT)
{
  const int chunk = blockIdx.x, b = chunk >> 4, c = chunk & 15;
  const int ty = blockIdx.y;
  const int m0 = (ty >> 2) * 128, n0 = (ty & 3) * 64;
  __shared__ u16 SA[8 * SLAB];
  __shared__ u16 SB[8 * SLABB];
  u16* Ah = SA; u16* Al = SA + 4 * SLAB;
  u16* Bh = SB; u16* Bl = SB + 4 * SLABB;
  const int tid = threadIdx.x, lane = tid & 63, wave = tid >> 6;
  const int wm0 = (wave >> 1) * 64, wn0 = (wave & 1) * 32;
  const int fm = lane & 15, fq = lane >> 4;
  const u16* AhP = VwTh + ((size_t)(b * 2 + (m0 >> 7)) * 512 + c * 32) * 1024;
  const u16* AlP = VwTl + ((size_t)(b * 2 + (m0 >> 7)) * 512 + c * 32) * 1024;
  const u16* BhP = KTh + ((size_t)(b * 2 + (n0 >> 7)) * 512 + c * 32) * 1024 + (size_t)(n0 & 127) * 8;
  const u16* BlP = KTl + ((size_t)(b * 2 + (n0 >> 7)) * 512 + c * 32) * 1024 + (size_t)(n0 & 127) * 8;
  f32x4 acc[4][2];
#pragma unroll
  for (int i = 0; i < 4; ++i)
#pragma unroll
    for (int j = 0; j < 2; ++j) acc[i][j] = (f32x4){0.f, 0.f, 0.f, 0.f};
  for (int ks = 0; ks < 8; ++ks) {
    __syncthreads();
    if (wave == 0) stage8kp(AhP + ks * 4096, Ah, lane);
    if (wave == 1) stage8kp(AlP + ks * 4096, Al, lane);
    if (wave == 2) stageB64(BhP + ks * 4096, Bh, lane);
    if (wave == 3) stageB64(BlP + ks * 4096, Bl, lane);
    __syncthreads();
    mfma_step_ab(Ah, Al, Bh, Bl, wm0, wn0, fm, fq, acc);
  }
#pragma unroll
  for (int i = 0; i < 4; ++i)
#pragma unroll
    for (int j = 0; j < 2; ++j)
#pragma unroll
      for (int r = 0; r < 4; ++r) {
        int e = m0 + wm0 + i * 16 + fq * 4 + r;
        int d = n0 + wn0 + j * 16 + fm;
        lMatT[(size_t)chunk * 65536 + (size_t)e * 256 + d] = acc[i][j][r];
      }
}

// 6) carry scan -> cM packed split
__global__ __launch_bounds__(256) void combine_mat_kernel(
    const float* __restrict__ lMatT, u16* __restrict__ cMh, u16* __restrict__ cMl)
{
  const int t = blockIdx.x * 256 + threadIdx.x;
  const int b = t >> 13, rem = t & 8191;
  const int k8 = rem >> 8, e = rem & 255;
  const float gL = powf(GAMMA, (float)LL);
  float s[8] = {0.f, 0.f, 0.f, 0.f, 0.f, 0.f, 0.f, 0.f};
  for (int ch = 0; ch < 16; ++ch) {
    size_t ro = (size_t)(b * 16 + ch) * 65536 + (size_t)e * 256 + k8 * 8;
    float4 a0 = *(const float4*)&lMatT[ro];
    float4 a1 = *(const float4*)&lMatT[ro + 4];
    float vals[8] = {a0.x, a0.y, a0.z, a0.w, a1.x, a1.y, a1.z, a1.w};
    u16 hh[8], ll[8];
#pragma unroll
    for (int u = 0; u < 8; ++u) {
      u16 h = f2bf(s[u]); hh[u] = h; ll[u] = f2bf(s[u] - bf2f(h));
    }
    size_t wo = ((size_t)(((b * 16 + ch) * 2 + (e >> 7)) * 32 + k8)) * 1024 + (size_t)(e & 127) * 8;
    *(short8*)&cMh[wo] = *(short8*)hh;
    *(short8*)&cMl[wo] = *(short8*)ll;
#pragma unroll
    for (int u = 0; u < 8; ++u) s[u] = gL * s[u] + vals[u];
  }
}

// ---------------------------------------------------------------------------
// 7) out = g^(il+1) * Q~ @ cM^T + Sg @ Vd ; 128x64 tiles (grid 64x8)
__global__ __launch_bounds__(256, 3) void out_kernel(
    const u16* __restrict__ Qh, const u16* __restrict__ Ql,
    const u16* __restrict__ cMh, const u16* __restrict__ cMl,
    const u16* __restrict__ Sgh, const u16* __restrict__ Sgl,
    const u16* __restrict__ VdTh, const u16* __restrict__ VdTl,
    float* __restrict__ out)
{
  const int chunk = blockIdx.x, b = chunk >> 4, c = chunk & 15;
  const int ty = blockIdx.y;
  const int m0 = (ty >> 2) * 128, n0 = (ty & 3) * 64;
  __shared__ u16 SA[8 * SLAB];
  __shared__ u16 SB[8 * SLABB];
  __shared__ float olut[128];
  u16* Ah = SA; u16* Al = SA + 4 * SLAB;
  u16* Bh = SB; u16* Bl = SB + 4 * SLABB;
  const int tid = threadIdx.x, lane = tid & 63, wave = tid >> 6;
  const int wm0 = (wave >> 1) * 64, wn0 = (wave & 1) * 32;
  const int fm = lane & 15, fq = lane >> 4;
  if (tid < 128) olut[tid] = exp2f((float)(m0 + tid + 1) * LOG2G);
  f32x4 acc[4][2];
#pragma unroll
  for (int i = 0; i < 4; ++i)
#pragma unroll
    for (int j = 0; j < 2; ++j) acc[i][j] = (f32x4){0.f, 0.f, 0.f, 0.f};
  {  // inter: A = Q panel, B = cM rows n0..n0+64
    const u16* AhP = Qh + (size_t)(b * 32 + c * 2 + (m0 >> 7)) * 32768;
    const u16* AlP = Ql + (size_t)(b * 32 + c * 2 + (m0 >> 7)) * 32768;
    const u16* BhP = cMh + (size_t)(chunk * 2 + (n0 >> 7)) * 32768 + (size_t)(n0 & 127) * 8;
    const u16* BlP = cMl + (size_t)(chunk * 2 + (n0 >> 7)) * 32768 + (size_t)(n0 & 127) * 8;
    for (int ks = 0; ks < 8; ++ks) {
      __syncthreads();
      if (wave == 0) stage8kp(AhP + ks * 4096, Ah, lane);
      if (wave == 1) stage8kp(AlP + ks * 4096, Al, lane);
      if (wave == 2) stageB64(BhP + ks * 4096, Bh, lane);
      if (wave == 3) stageB64(BlP + ks * 4096, Bl, lane);
      __syncthreads();
      mfma_step_ab(Ah, Al, Bh, Bl, wm0, wn0, fm, fq, acc);
    }
  }
#pragma unroll
  for (int i = 0; i < 4; ++i)
#pragma unroll
    for (int r = 0; r < 4; ++r) {
      int rl = wm0 + i * 16 + fq * 4 + r;
      float sc = olut[rl];
#pragma unroll
      for (int j = 0; j < 2; ++j) acc[i][j][r] *= sc;
    }
  {  // intra: A = Sg panel, B = Vd rows n0..n0+64; k bounded by causality
    const u16* AhP = Sgh + (size_t)(chunk * 2 + (m0 >> 7)) * 32768;
    const u16* AlP = Sgl + (size_t)(chunk * 2 + (m0 >> 7)) * 32768;
    const u16* BhP = VdTh + ((size_t)(b * 2 + (n0 >> 7)) * 512 + c * 32) * 1024 + (size_t)(n0 & 127) * 8;
    const u16* BlP = VdTl + ((size_t)(b * 2 + (n0 >> 7)) * 512 + c * 32) * 1024 + (size_t)(n0 & 127) * 8;
    const int nks = (m0 >> 5) + 4;
    for (int ks = 0; ks < nks; ++ks) {
      __syncthreads();
      if (wave == 0) stage8kp(AhP + ks * 4096, Ah, lane);
      if (wave == 1) stage8kp(AlP + ks * 4096, Al, lane);
      if (wave == 2) stageB64(BhP + ks * 4096, Bh, lane);
      if (wave == 3) stageB64(BlP + ks * 4096, Bl, lane);
      __syncthreads();
      mfma_step_ab(Ah, Al, Bh, Bl, wm0, wn0, fm, fq, acc);
    }
  }
#pragma unroll
  for (int i = 0; i < 4; ++i)
#pragma unroll
    for (int j = 0; j < 2; ++j)
#pragma unroll
      for (int r = 0; r < 4; ++r) {
        int il = m0 + wm0 + i * 16 + fq * 4 + r;
        int e = n0 + wn0 + j * 16 + fm;
        out[(size_t)(b * SS + c * LL + il) * DD + e] = acc[i][j][r];
      }
}

// ---------------------------------------------------------------------------
extern "C" void kernel_launch(void* const* d_in, const int* in_sizes, int n_in,
                              void* d_out, int out_size, void* d_ws, size_t ws_size,
                              hipStream_t stream) {
  const float* xq = (const float*)d_in[0];
  const float* xk = (const float*)d_in[1];
  const float* xv = (const float*)d_in[2];
  const float* Wq = (const float*)d_in[3];
  const float* bq = (const float*)d_in[4];
  const float* Wk = (const float*)d_in[5];
  const float* bk = (const float*)d_in[6];
  const float* Wv = (const float*)d_in[7];
  const float* bv = (const float*)d_in[8];
  float* out = (float*)d_out;

  char* p = (char*)d_ws;
  const size_t H16 = (size_t)BB * SS * DD * 2;  // 8 MB
  u16* Qh   = (u16*)(p + 0 * H16);  u16* Ql   = (u16*)(p + 1 * H16);
  u16* Kh   = (u16*)(p + 2 * H16);  u16* Kl   = (u16*)(p + 3 * H16);
  u16* KTh  = (u16*)(p + 4 * H16);  u16* KTl  = (u16*)(p + 5 * H16);
  u16* VdTh = (u16*)(p + 6 * H16);  u16* VdTl = (u16*)(p + 7 * H16);
  u16* VwTh = (u16*)(p + 8 * H16);  u16* VwTl = (u16*)(p + 9 * H16);
  u16* Sgh  = (u16*)(p + 10 * H16); u16* Sgl  = (u16*)(p + 11 * H16);
  u16* cMh  = (u16*)(p + 12 * H16); u16* cMl  = (u16*)(p + 13 * H16);
  float* lMatT = (float*)(p + 14 * H16);
  float* VT32  = (float*)(p + 16 * H16);
  u16* Wth = (u16*)(p + 18 * H16);
  u16* Wtl = (u16*)(p + 18 * H16 + 3 * DD * DD * 2);
  float* rsP  = (float*)(p + 18 * H16 + 6 * DD * DD * 2);
  float* lVec = rsP + (size_t)BB * SS;
  float* cVec = lVec + (size_t)BB * NCH * DD;
  u16* Xh = (u16*)(p + 10 * H16);
  u16* Xl = (u16*)(p + 13 * H16);

  splitXW_kernel<<<dim3(129, 3), 256, 0, stream>>>(
      xq, xk, xv, Wq, Wk, Wv, Xh, Xl, Wth, Wtl, rsP);
  proj_kernel<<<dim3(BB * SS / 128, 2, 3), 256, 0, stream>>>(
      Xh, Xl, Wth, Wtl, bq, bk, bv, Qh, Ql, Kh, Kl, KTh, KTl, VT32);
  local_vec_kernel<<<BB * NCH, 256, 0, stream>>>(KTh, KTl, lVec);
  combine_vec_kernel<<<BB, 256, 0, stream>>>(lVec, cVec);
  scores_kernel<<<dim3(BB * NCH, 6), 256, 0, stream>>>(
      Qh, Ql, Kh, Kl, cVec, Sgh, Sgl, rsP);
  vscale_kernel<<<256, 256, 0, stream>>>(VT32, rsP, VdTh, VdTl, VwTh, VwTl);
  lmat_kernel<<<dim3(BB * NCH, 8), 256, 0, stream>>>(VwTh, VwTl, KTh, KTl, lMatT);
  combine_mat_kernel<<<128, 256, 0, stream>>>(lMatT, cMh, cMl);
  out_kernel<<<dim3(BB * NCH, 8), 256, 0, stream>>>(
      Qh, Ql, cMh, cMl, Sgh, Sgl, VdTh, VdTl, out);
}